// Round 2
// baseline (2110.533 us; speedup 1.0000x reference)
//
#include <hip/hip_runtime.h>

#define BATCH 4096
#define HALF_B 2048
#define IN_DIM 1024
#define HID 16384
#define KTOP 64
#define KAUX 512
#define LN_EPS 1e-5f
#define TIE_CAP 768

typedef short s16x8 __attribute__((ext_vector_type(8)));
typedef _Float16 f16x8 __attribute__((ext_vector_type(8)));
typedef float f32x4 __attribute__((ext_vector_type(4)));

__device__ __forceinline__ ushort f2bf(float f) {
  unsigned u = __float_as_uint(f);
  u += 0x7FFFu + ((u >> 16) & 1u);   // RNE
  return (ushort)(u >> 16);
}
__device__ __forceinline__ float bf2f(ushort h) {
  return __uint_as_float(((unsigned)h) << 16);
}
__device__ __forceinline__ ushort f2h_bits(float v) {
  _Float16 h = (_Float16)v;
  return __builtin_bit_cast(ushort, h);
}
__device__ __forceinline__ float h2f(ushort bits) {
  return (float)__builtin_bit_cast(_Float16, bits);
}

__device__ __forceinline__ void gl_lds16(const void* g, void* l) {
  __builtin_amdgcn_global_load_lds(
      (const __attribute__((address_space(1))) unsigned*)g,
      (__attribute__((address_space(3))) unsigned*)l, 16, 0, 0);
}

__device__ __forceinline__ float block_sum_f(float v) {
  __shared__ float redf[4];
  for (int o = 32; o > 0; o >>= 1) v += __shfl_down(v, o, 64);
  int lane = threadIdx.x & 63, w = threadIdx.x >> 6;
  if (lane == 0) redf[w] = v;
  __syncthreads();
  float t = (redf[0] + redf[1]) + (redf[2] + redf[3]);
  __syncthreads();
  return t;
}

__device__ __forceinline__ int block_sum_i(int v) {
  __shared__ int redi[4];
  for (int o = 32; o > 0; o >>= 1) v += __shfl_down(v, o, 64);
  int lane = threadIdx.x & 63, w = threadIdx.x >> 6;
  if (lane == 0) redi[w] = v;
  __syncthreads();
  int t = (redi[0] + redi[1]) + (redi[2] + redi[3]);
  __syncthreads();
  return t;
}

// ---------------- LayerNorm -> x_norm (scaled f16 hi/lo split), mu, std ----------------
// AH = f16(xn * 2^10), AL = f16((xn - AH*2^-10) * 2^21)
__global__ __launch_bounds__(256) void ln_kernel(
    const float* __restrict__ x, const float* __restrict__ b_pre,
    ushort* __restrict__ xh, ushort* __restrict__ xl,
    float* __restrict__ mu, float* __restrict__ stdv)
{
  int r = blockIdx.x, t = threadIdx.x;
  float4 v = ((const float4*)(x + (size_t)r * IN_DIM))[t];
  float s = (v.x + v.y) + (v.z + v.w);
  float mean = block_sum_f(s) * (1.0f / IN_DIM);
  float dx = v.x - mean, dy = v.y - mean, dz = v.z - mean, dw = v.w - mean;
  float ss = (dx*dx + dy*dy) + (dz*dz + dw*dw);
  float var = block_sum_f(ss) * (1.0f / (IN_DIM - 1));   // ddof = 1
  float sd = sqrtf(var);
  float inv = 1.0f / (sd + LN_EPS);
  float4 bp = ((const float4*)b_pre)[t];
  float xn[4] = { dx*inv - bp.x, dy*inv - bp.y, dz*inv - bp.z, dw*inv - bp.w };
  ushort hb[4], lb[4];
  #pragma unroll
  for (int i = 0; i < 4; ++i) {
    _Float16 hh = (_Float16)(xn[i] * 1024.0f);
    float rem = fmaf(-(float)hh, 0.0009765625f, xn[i]);       // xn - AH*2^-10
    hb[i] = __builtin_bit_cast(ushort, hh);
    lb[i] = f2h_bits(rem * 2097152.0f);                        // * 2^21
  }
  *(ushort4*)(xh + (size_t)r * IN_DIM + t * 4) = make_ushort4(hb[0], hb[1], hb[2], hb[3]);
  *(ushort4*)(xl + (size_t)r * IN_DIM + t * 4) = make_ushort4(lb[0], lb[1], lb[2], lb[3]);
  if (t == 0) { mu[r] = mean; stdv[r] = sd; }
}

// ---------------- transpose f32 [R][C] -> [C][R]  ----------------
// MODE 0: scaled f16 hi/lo split (BH = f16(v*2^13), BL = f16(rem*2^24))
// MODE 1: bf16 single
template<int MODE>
__global__ __launch_bounds__(256) void transpose_k(
    const float* __restrict__ in, ushort* __restrict__ oh, ushort* __restrict__ ol,
    int R, int C)
{
  __shared__ float tile[32][33];
  int c0 = blockIdx.x * 32, r0 = blockIdx.y * 32;
  int t = threadIdx.x;
  int col = t & 31, rbase = t >> 5;
  #pragma unroll
  for (int rep = 0; rep < 4; ++rep) {
    int rr = rbase + rep * 8;
    tile[rr][col] = in[(size_t)(r0 + rr) * C + c0 + col];
  }
  __syncthreads();
  int j = t & 31, ibase = t >> 5;
  #pragma unroll
  for (int rep = 0; rep < 4; ++rep) {
    int i = ibase + rep * 8;
    float v = tile[j][i];
    size_t o = (size_t)(c0 + i) * R + r0 + j;
    if constexpr (MODE == 0) {
      _Float16 hh = (_Float16)(v * 8192.0f);
      float rem = fmaf(-(float)hh, 1.220703125e-4f, v);        // v - BH*2^-13
      oh[o] = __builtin_bit_cast(ushort, hh);
      ol[o] = f2h_bits(rem * 16777216.0f);                     // * 2^24
    } else {
      oh[o] = f2bf(v);
    }
  }
}

// ---------------- encoder GEMM: pre = xn @ w_enc + b_enc, scaled f16 3-term split ---
// A planes [M][K] f16-bits, B planes [N][K] f16-bits.
// acc1 = AH*BH (scale 2^-23); acc2 = AH*BL + AL*BH (scale 2^-34)
__global__ __launch_bounds__(256) void gemm_enc(
    const ushort* __restrict__ Ah, const ushort* __restrict__ Al,
    const ushort* __restrict__ Bh, const ushort* __restrict__ Bl,
    float* __restrict__ C, const float* __restrict__ bias,
    int M, int N, int K)
{
  __shared__ ushort lds[4 * 128 * 64];
  ushort* As  = lds;
  ushort* Bs  = lds + 128 * 64;
  ushort* As2 = lds + 2 * 128 * 64;
  ushort* Bs2 = lds + 3 * 128 * 64;

  const int tid = threadIdx.x, w = tid >> 6, lane = tid & 63;
  const int bm0 = blockIdx.y * 128, bn0 = blockIdx.x * 128;
  const int wm = w >> 1, wn = w & 1;
  const int fr = lane & 15, fq = lane >> 4;
  const int srow = lane >> 3, scol = (lane & 7) * 8;

  f32x4 acc1[4][4] = {};
  f32x4 acc2[4][4] = {};
  const int nk = K >> 6;
  for (int kt = 0; kt < nk; ++kt) {
    const int k0 = kt << 6;
    __syncthreads();
    #pragma unroll
    for (int i = 0; i < 4; ++i) {
      int rr = (i * 4 + w) * 8 + srow;
      gl_lds16(Ah + (size_t)(bm0 + rr) * K + k0 + scol, &As [(i * 4 + w) * 512]);
      gl_lds16(Bh + (size_t)(bn0 + rr) * K + k0 + scol, &Bs [(i * 4 + w) * 512]);
      gl_lds16(Al + (size_t)(bm0 + rr) * K + k0 + scol, &As2[(i * 4 + w) * 512]);
      gl_lds16(Bl + (size_t)(bn0 + rr) * K + k0 + scol, &Bs2[(i * 4 + w) * 512]);
    }
    __syncthreads();
    #pragma unroll
    for (int ks = 0; ks < 2; ++ks) {
      f16x8 ah[4], bh[4], al[4], bl[4];
      #pragma unroll
      for (int i = 0; i < 4; ++i) {
        int ar = wm * 64 + i * 16 + fr;
        int br = wn * 64 + i * 16 + fr;
        int co = ks * 32 + fq * 8;
        ah[i] = *reinterpret_cast<const f16x8*>(&As [ar * 64 + co]);
        bh[i] = *reinterpret_cast<const f16x8*>(&Bs [br * 64 + co]);
        al[i] = *reinterpret_cast<const f16x8*>(&As2[ar * 64 + co]);
        bl[i] = *reinterpret_cast<const f16x8*>(&Bs2[br * 64 + co]);
      }
      #pragma unroll
      for (int mi = 0; mi < 4; ++mi)
        #pragma unroll
        for (int ni = 0; ni < 4; ++ni) {
          acc1[mi][ni] = __builtin_amdgcn_mfma_f32_16x16x32_f16(ah[mi], bh[ni], acc1[mi][ni], 0, 0, 0);
          acc2[mi][ni] = __builtin_amdgcn_mfma_f32_16x16x32_f16(ah[mi], bl[ni], acc2[mi][ni], 0, 0, 0);
          acc2[mi][ni] = __builtin_amdgcn_mfma_f32_16x16x32_f16(al[mi], bh[ni], acc2[mi][ni], 0, 0, 0);
        }
    }
  }
  #pragma unroll
  for (int mi = 0; mi < 4; ++mi) {
    int grow_b = bm0 + wm * 64 + mi * 16 + fq * 4;
    #pragma unroll
    for (int ni = 0; ni < 4; ++ni) {
      int gcol = bn0 + wn * 64 + ni * 16 + fr;
      #pragma unroll
      for (int q = 0; q < 4; ++q) {
        float v = acc1[mi][ni][q] * 1.1920929e-07f      // 2^-23
                + acc2[mi][ni][q] * 5.8207661e-11f      // 2^-34
                + bias[gcol];
        C[(size_t)(grow_b + q) * N + gcol] = v;
      }
    }
  }
}

// ---------------- decoder GEMM (bf16): out = A2 @ w_dec, epi: (acc+bias)*std+mu ----
__global__ __launch_bounds__(256) void gemm_dec(
    const ushort* __restrict__ A, const ushort* __restrict__ B,
    float* __restrict__ C, const float* __restrict__ bias,
    const float* __restrict__ stdv, const float* __restrict__ muv,
    int M, int N, int K)
{
  __shared__ ushort lds[2 * 128 * 64];
  ushort* As = lds;
  ushort* Bs = lds + 128 * 64;

  const int tid = threadIdx.x, w = tid >> 6, lane = tid & 63;
  const int bm0 = blockIdx.y * 128, bn0 = blockIdx.x * 128;
  const int wm = w >> 1, wn = w & 1;
  const int fr = lane & 15, fq = lane >> 4;
  const int srow = lane >> 3, scol = (lane & 7) * 8;

  f32x4 acc[4][4] = {};
  const int nk = K >> 6;
  for (int kt = 0; kt < nk; ++kt) {
    const int k0 = kt << 6;
    __syncthreads();
    #pragma unroll
    for (int i = 0; i < 4; ++i) {
      int rr = (i * 4 + w) * 8 + srow;
      gl_lds16(A + (size_t)(bm0 + rr) * K + k0 + scol, &As[(i * 4 + w) * 512]);
      gl_lds16(B + (size_t)(bn0 + rr) * K + k0 + scol, &Bs[(i * 4 + w) * 512]);
    }
    __syncthreads();
    #pragma unroll
    for (int ks = 0; ks < 2; ++ks) {
      s16x8 ah[4], bh[4];
      #pragma unroll
      for (int i = 0; i < 4; ++i) {
        int ar = wm * 64 + i * 16 + fr;
        int br = wn * 64 + i * 16 + fr;
        int co = ks * 32 + fq * 8;
        ah[i] = *(const s16x8*)&As[ar * 64 + co];
        bh[i] = *(const s16x8*)&Bs[br * 64 + co];
      }
      #pragma unroll
      for (int mi = 0; mi < 4; ++mi)
        #pragma unroll
        for (int ni = 0; ni < 4; ++ni)
          acc[mi][ni] = __builtin_amdgcn_mfma_f32_16x16x32_bf16(ah[mi], bh[ni], acc[mi][ni], 0, 0, 0);
    }
  }
  #pragma unroll
  for (int mi = 0; mi < 4; ++mi) {
    int grow_b = bm0 + wm * 64 + mi * 16 + fq * 4;
    #pragma unroll
    for (int ni = 0; ni < 4; ++ni) {
      int gcol = bn0 + wn * 64 + ni * 16 + fr;
      #pragma unroll
      for (int q = 0; q < 4; ++q) {
        int grow = grow_b + q;
        float v = (acc[mi][ni][q] + bias[gcol]) * stdv[grow] + muv[grow];
        C[(size_t)grow * N + gcol] = v;
      }
    }
  }
}

// ---------------- per-row exact top-64 & top-512 via 32-pass radix bisection -------
__device__ __forceinline__ unsigned key_of(float f) {
  unsigned u = __float_as_uint(f);
  return (u & 0x80000000u) ? ~u : (u | 0x80000000u);
}
__device__ __forceinline__ float val_of(unsigned k) {
  unsigned u = (k & 0x80000000u) ? (k & 0x7FFFFFFFu) : ~k;
  return __uint_as_float(u);
}

__global__ __launch_bounds__(256) void topk_kernel(
    const float* __restrict__ pre, int r0,
    int* __restrict__ midx, float* __restrict__ mval,
    int* __restrict__ aidx, ushort* __restrict__ aval,
    int* __restrict__ fired)
{
  const int rl = blockIdx.x, t = threadIdx.x;
  const int r = r0 + rl;
  __shared__ unsigned keys[HID];
  __shared__ int tie64[TIE_CAP], tie512[TIE_CAP];
  __shared__ int cm, ca, c64, c512;

  const float4* src = (const float4*)(pre + (size_t)rl * HID);
  for (int i = t; i < HID / 4; i += 256) {
    float4 v = src[i];
    uint4 kk;
    kk.x = key_of(v.x); kk.y = key_of(v.y); kk.z = key_of(v.z); kk.w = key_of(v.w);
    ((uint4*)keys)[i] = kk;
  }
  if (t == 0) { cm = 0; ca = 0; c64 = 0; c512 = 0; }
  __syncthreads();

  unsigned T64 = 0, T512 = 0;
  for (int bit = 31; bit >= 0; --bit) {
    unsigned m64 = T64 | (1u << bit), m512 = T512 | (1u << bit);
    int n = 0;
    for (int i = t; i < HID; i += 256) {
      unsigned k = keys[i];
      n += (k >= m64) ? 1 : 0;
      n += (k >= m512) ? 0x10000 : 0;
    }
    n = block_sum_i(n);
    if ((n & 0xFFFF) >= KTOP) T64 = m64;
    if ((unsigned)(n >> 16) >= KAUX) T512 = m512;
  }

  for (int i = t; i < HID; i += 256) {
    unsigned k = keys[i];
    if (k > T512) {
      int p = atomicAdd(&ca, 1);
      float v = val_of(k);
      aidx[(size_t)r * KAUX + p] = i;
      aval[(size_t)r * KAUX + p] = f2bf(v > 0.f ? v : 0.f);
    } else if (k == T512) {
      int p = atomicAdd(&c512, 1);
      if (p < TIE_CAP) tie512[p] = i;
    }
    if (k > T64) {
      int p = atomicAdd(&cm, 1);
      float v = val_of(k);
      midx[(size_t)r * KTOP + p] = i;
      mval[(size_t)r * KTOP + p] = v > 0.f ? v : 0.f;
      if (v > 0.f) fired[i] = 1;
    } else if (k == T64) {
      int p = atomicAdd(&c64, 1);
      if (p < TIE_CAP) tie64[p] = i;
    }
  }
  __syncthreads();

  if (t == 0) {  // append lowest-index ties for main
    int have = cm, nt = c64 < TIE_CAP ? c64 : TIE_CAP, need = KTOP - have;
    float v = val_of(T64); float rv = v > 0.f ? v : 0.f;
    for (int q = 0; q < need; ++q) {
      int best = 0x7FFFFFFF, bi = -1;
      for (int u = 0; u < nt; ++u) if (tie64[u] < best) { best = tie64[u]; bi = u; }
      if (bi < 0) break;
      tie64[bi] = 0x7FFFFFFF;
      midx[(size_t)r * KTOP + have + q] = best;
      mval[(size_t)r * KTOP + have + q] = rv;
      if (v > 0.f) fired[best] = 1;
    }
  }
  if (t == 64) {  // append lowest-index ties for aux
    int have = ca, nt = c512 < TIE_CAP ? c512 : TIE_CAP, need = KAUX - have;
    float v = val_of(T512); float rv = v > 0.f ? v : 0.f;
    ushort rb = f2bf(rv);
    for (int q = 0; q < need; ++q) {
      int best = 0x7FFFFFFF, bi = -1;
      for (int u = 0; u < nt; ++u) if (tie512[u] < best) { best = tie512[u]; bi = u; }
      if (bi < 0) break;
      tie512[bi] = 0x7FFFFFFF;
      aidx[(size_t)r * KAUX + have + q] = best;
      aval[(size_t)r * KAUX + have + q] = rb;
    }
  }
}

// ---------------- stats / num_dead ----------------
__global__ __launch_bounds__(256) void stats_kernel(
    const int* __restrict__ fired, const int* __restrict__ sln, float* __restrict__ nd_out)
{
  int t = threadIdx.x, c = 0;
  for (int j = t; j < HID; j += 256) {
    int dead = (fired[j] == 0) ? 1 : 0;
    int stats = sln[j] * dead + 1;
    if ((float)stats > (2000.0f / 4096.0f)) c++;
  }
  c = block_sum_i(c);
  if (t == 0) nd_out[0] = (float)c;
}

// ---------------- scatter aux latents into dense bf16 matrix ----------------
__global__ __launch_bounds__(256) void scatter_aux(
    const int* __restrict__ aidx, const ushort* __restrict__ aval, ushort* __restrict__ A2)
{
  int g = blockIdx.x * 256 + threadIdx.x;
  int r = g >> 9;
  int j = aidx[g];
  A2[(size_t)r * HID + j] = aval[g];
}

// ---------------- main decode: sparse gather, f32 exact ----------------
__global__ __launch_bounds__(256) void decode_main(
    const int* __restrict__ midx, const float* __restrict__ mval,
    const float* __restrict__ wdec, const float* __restrict__ b_pre,
    const float* __restrict__ stdv, const float* __restrict__ muv,
    float* __restrict__ out)
{
  int r = blockIdx.x, t = threadIdx.x;
  __shared__ int sj[KTOP];
  __shared__ float sv[KTOP];
  if (t < KTOP) { sj[t] = midx[(size_t)r * KTOP + t]; sv[t] = mval[(size_t)r * KTOP + t]; }
  __syncthreads();
  float ax = 0.f, ay = 0.f, az = 0.f, aw = 0.f;
  for (int i = 0; i < KTOP; ++i) {
    float v = sv[i];
    const float4* wrow = (const float4*)(wdec + (size_t)sj[i] * IN_DIM);
    float4 wv = wrow[t];
    ax += v * wv.x; ay += v * wv.y; az += v * wv.z; aw += v * wv.w;
  }
  float4 bp = ((const float4*)b_pre)[t];
  float s = stdv[r], m = muv[r];
  float4 o;
  o.x = (ax + bp.x) * s + m;
  o.y = (ay + bp.y) * s + m;
  o.z = (az + bp.z) * s + m;
  o.w = (aw + bp.w) * s + m;
  ((float4*)(out + (size_t)r * IN_DIM))[t] = o;
}

__global__ void diag_kernel(float* p, float v) { p[0] = v; }

// ---------------- launch ----------------
extern "C" void kernel_launch(void* const* d_in, const int* in_sizes, int n_in,
                              void* d_out, int out_size, void* d_ws, size_t ws_size,
                              hipStream_t stream)
{
  const float* x     = (const float*)d_in[0];
  const float* w_enc = (const float*)d_in[1];
  const float* w_dec = (const float*)d_in[2];
  const float* b_enc = (const float*)d_in[3];
  const float* b_pre = (const float*)d_in[4];
  const int*   sln   = (const int*)d_in[5];

  float* out0 = (float*)d_out;                          // recons [4096][1024]
  float* out1 = out0 + (size_t)BATCH * IN_DIM;          // aux_recons
  float* out2 = out0 + 2 * (size_t)BATCH * IN_DIM;      // num_dead (as f32)

  char* ws = (char*)d_ws;
  size_t off = 0;
  auto take = [&](size_t bytes) { char* p = ws + off; off += (bytes + 255) & ~(size_t)255; return p; };

  // pre (half-batch f32) aliases A2 (full-batch bf16): both 128 MB
  float*  pre      = (float*)take((size_t)HALF_B * HID * 4);
  ushort* A2       = (ushort*)pre;
  ushort* wencT_h  = (ushort*)take((size_t)HID * IN_DIM * 2);
  ushort* wencT_l  = (ushort*)take((size_t)HID * IN_DIM * 2);
  ushort* wdecT_h  = (ushort*)take((size_t)HID * IN_DIM * 2);
  ushort* xh       = (ushort*)take((size_t)BATCH * IN_DIM * 2);
  ushort* xl       = (ushort*)take((size_t)BATCH * IN_DIM * 2);
  float*  mu       = (float*)take(BATCH * 4);
  float*  stdv     = (float*)take(BATCH * 4);
  int*    midx     = (int*)take((size_t)BATCH * KTOP * 4);
  float*  mval     = (float*)take((size_t)BATCH * KTOP * 4);
  int*    aidx     = (int*)take((size_t)BATCH * KAUX * 4);
  ushort* aval     = (ushort*)take((size_t)BATCH * KAUX * 2);
  int*    fired    = (int*)take(HID * 4);

  if (ws_size < off) {  // diagnostic: report actual ws_size through num_dead slot
    diag_kernel<<<1, 1, 0, stream>>>(out2, (float)ws_size);
    return;
  }

  ln_kernel<<<BATCH, 256, 0, stream>>>(x, b_pre, xh, xl, mu, stdv);
  transpose_k<0><<<dim3(HID / 32, IN_DIM / 32), 256, 0, stream>>>(w_enc, wencT_h, wencT_l, IN_DIM, HID);
  transpose_k<1><<<dim3(IN_DIM / 32, HID / 32), 256, 0, stream>>>(w_dec, wdecT_h, nullptr, HID, IN_DIM);
  hipMemsetAsync(fired, 0, HID * sizeof(int), stream);

  for (int half = 0; half < 2; ++half) {
    const ushort* Ah = xh + (size_t)half * HALF_B * IN_DIM;
    const ushort* Al = xl + (size_t)half * HALF_B * IN_DIM;
    gemm_enc<<<dim3(HID / 128, HALF_B / 128), 256, 0, stream>>>(
        Ah, Al, wencT_h, wencT_l, pre, b_enc, HALF_B, HID, IN_DIM);
    topk_kernel<<<HALF_B, 256, 0, stream>>>(pre, half * HALF_B, midx, mval, aidx, aval, fired);
  }
  stats_kernel<<<1, 256, 0, stream>>>(fired, sln, out2);

  hipMemsetAsync(A2, 0, (size_t)BATCH * HID * 2, stream);   // pre dead now
  scatter_aux<<<(BATCH * KAUX) / 256, 256, 0, stream>>>(aidx, aval, A2);

  gemm_dec<<<dim3(IN_DIM / 128, BATCH / 128), 256, 0, stream>>>(
      A2, wdecT_h, out1, b_pre, stdv, mu, BATCH, IN_DIM, HID);

  decode_main<<<BATCH, 256, 0, stream>>>(midx, mval, w_dec, b_pre, stdv, mu, out0);
}

// Round 3
// 1375.597 us; speedup vs baseline: 1.5343x; 1.5343x over previous
//
#include <hip/hip_runtime.h>

#define BATCH 4096
#define HALF_B 2048
#define IN_DIM 1024
#define HID 16384
#define KTOP 64
#define KAUX 512
#define KSPLIT 4
#define LN_EPS 1e-5f
#define TIE_CAP 768

typedef short s16x8 __attribute__((ext_vector_type(8)));
typedef float f32x4 __attribute__((ext_vector_type(4)));

__device__ __forceinline__ ushort f2bf(float f) {
  unsigned u = __float_as_uint(f);
  u += 0x7FFFu + ((u >> 16) & 1u);   // RNE
  return (ushort)(u >> 16);
}
__device__ __forceinline__ float bf2f(ushort h) {
  return __uint_as_float(((unsigned)h) << 16);
}

__device__ __forceinline__ void gl_lds16(const void* g, void* l) {
  __builtin_amdgcn_global_load_lds(
      (const __attribute__((address_space(1))) unsigned*)g,
      (__attribute__((address_space(3))) unsigned*)l, 16, 0, 0);
}

__device__ __forceinline__ float block_sum_f(float v) {
  __shared__ float redf[4];
  for (int o = 32; o > 0; o >>= 1) v += __shfl_down(v, o, 64);
  int lane = threadIdx.x & 63, w = threadIdx.x >> 6;
  if (lane == 0) redf[w] = v;
  __syncthreads();
  float t = (redf[0] + redf[1]) + (redf[2] + redf[3]);
  __syncthreads();
  return t;
}

__device__ __forceinline__ int block_sum_i(int v) {
  __shared__ int redi[4];
  for (int o = 32; o > 0; o >>= 1) v += __shfl_down(v, o, 64);
  int lane = threadIdx.x & 63, w = threadIdx.x >> 6;
  if (lane == 0) redi[w] = v;
  __syncthreads();
  int t = (redi[0] + redi[1]) + (redi[2] + redi[3]);
  __syncthreads();
  return t;
}

// ---------------- LayerNorm -> x_norm bf16, mu, std ----------------
__global__ __launch_bounds__(256) void ln_kernel(
    const float* __restrict__ x, const float* __restrict__ b_pre,
    ushort* __restrict__ xh, float* __restrict__ mu, float* __restrict__ stdv)
{
  int r = blockIdx.x, t = threadIdx.x;
  float4 v = ((const float4*)(x + (size_t)r * IN_DIM))[t];
  float s = (v.x + v.y) + (v.z + v.w);
  float mean = block_sum_f(s) * (1.0f / IN_DIM);
  float dx = v.x - mean, dy = v.y - mean, dz = v.z - mean, dw = v.w - mean;
  float ss = (dx*dx + dy*dy) + (dz*dz + dw*dw);
  float var = block_sum_f(ss) * (1.0f / (IN_DIM - 1));   // ddof = 1
  float sd = sqrtf(var);
  float inv = 1.0f / (sd + LN_EPS);
  float4 bp = ((const float4*)b_pre)[t];
  ushort h0 = f2bf(dx*inv - bp.x), h1 = f2bf(dy*inv - bp.y);
  ushort h2 = f2bf(dz*inv - bp.z), h3 = f2bf(dw*inv - bp.w);
  *(ushort4*)(xh + (size_t)r * IN_DIM + t * 4) = make_ushort4(h0, h1, h2, h3);
  if (t == 0) { mu[r] = mean; stdv[r] = sd; }
}

// ---------------- transpose f32 [R][C] -> bf16 [C][R] ----------------
__global__ __launch_bounds__(256) void transpose_k(
    const float* __restrict__ in, ushort* __restrict__ oh, int R, int C)
{
  __shared__ float tile[32][33];
  int c0 = blockIdx.x * 32, r0 = blockIdx.y * 32;
  int t = threadIdx.x;
  int col = t & 31, rbase = t >> 5;
  #pragma unroll
  for (int rep = 0; rep < 4; ++rep) {
    int rr = rbase + rep * 8;
    tile[rr][col] = in[(size_t)(r0 + rr) * C + c0 + col];
  }
  __syncthreads();
  int j = t & 31, ibase = t >> 5;
  #pragma unroll
  for (int rep = 0; rep < 4; ++rep) {
    int i = ibase + rep * 8;
    oh[(size_t)(c0 + i) * R + r0 + j] = f2bf(tile[j][i]);
  }
}

// ---------------- GEMM C = A @ B^T, bf16 MFMA, 128x128 tile ----------------
// MODE 0: C f32 = acc + bias[n]                       (encoder)
// MODE 1: C bf16 partial (split-K via blockIdx.z)     (decoder)
template<int MODE>
__global__ __launch_bounds__(256) void gemm128(
    const ushort* __restrict__ A, const ushort* __restrict__ B,
    float* __restrict__ Cf, ushort* __restrict__ Cb,
    const float* __restrict__ bias, int M, int N, int K, int kchunk)
{
  __shared__ ushort lds[2 * 128 * 64];
  ushort* As = lds;
  ushort* Bs = lds + 128 * 64;

  const int tid = threadIdx.x, w = tid >> 6, lane = tid & 63;
  const int bm0 = blockIdx.y * 128, bn0 = blockIdx.x * 128;
  const int wm = w >> 1, wn = w & 1;
  const int fr = lane & 15, fq = lane >> 4;
  const int srow = lane >> 3, scol = (lane & 7) * 8;
  const int kbeg = blockIdx.z * kchunk;

  f32x4 acc[4][4] = {};
  const int nk = kchunk >> 6;
  for (int kt = 0; kt < nk; ++kt) {
    const int k0 = kbeg + (kt << 6);
    __syncthreads();
    #pragma unroll
    for (int i = 0; i < 4; ++i) {
      int rr = (i * 4 + w) * 8 + srow;
      gl_lds16(A + (size_t)(bm0 + rr) * K + k0 + scol, &As[(i * 4 + w) * 512]);
      gl_lds16(B + (size_t)(bn0 + rr) * K + k0 + scol, &Bs[(i * 4 + w) * 512]);
    }
    __syncthreads();
    #pragma unroll
    for (int ks = 0; ks < 2; ++ks) {
      s16x8 ah[4], bh[4];
      #pragma unroll
      for (int i = 0; i < 4; ++i) {
        int ar = wm * 64 + i * 16 + fr;
        int br = wn * 64 + i * 16 + fr;
        int co = ks * 32 + fq * 8;
        ah[i] = *(const s16x8*)&As[ar * 64 + co];
        bh[i] = *(const s16x8*)&Bs[br * 64 + co];
      }
      #pragma unroll
      for (int mi = 0; mi < 4; ++mi)
        #pragma unroll
        for (int ni = 0; ni < 4; ++ni)
          acc[mi][ni] = __builtin_amdgcn_mfma_f32_16x16x32_bf16(ah[mi], bh[ni], acc[mi][ni], 0, 0, 0);
    }
  }
  #pragma unroll
  for (int mi = 0; mi < 4; ++mi) {
    int grow_b = bm0 + wm * 64 + mi * 16 + fq * 4;
    #pragma unroll
    for (int ni = 0; ni < 4; ++ni) {
      int gcol = bn0 + wn * 64 + ni * 16 + fr;
      #pragma unroll
      for (int q = 0; q < 4; ++q) {
        int grow = grow_b + q;
        if constexpr (MODE == 0) {
          Cf[(size_t)grow * N + gcol] = acc[mi][ni][q] + bias[gcol];
        } else {
          Cb[((size_t)blockIdx.z * M + grow) * N + gcol] = f2bf(acc[mi][ni][q]);
        }
      }
    }
  }
}

// ---------------- reduce split-K partials + decoder epilogue ----------------
__global__ __launch_bounds__(256) void reduce_dec(
    const ushort* __restrict__ P, const float* __restrict__ b_pre,
    const float* __restrict__ stdv, const float* __restrict__ muv,
    float* __restrict__ out)
{
  int gid = blockIdx.x * 256 + threadIdx.x;
  size_t e0 = (size_t)gid * 4;
  int r = (int)(e0 >> 10), c = (int)(e0 & 1023);
  float sx = 0.f, sy = 0.f, sz = 0.f, sw = 0.f;
  #pragma unroll
  for (int ks = 0; ks < KSPLIT; ++ks) {
    ushort4 p = *(const ushort4*)&P[(size_t)ks * BATCH * IN_DIM + e0];
    sx += bf2f(p.x); sy += bf2f(p.y); sz += bf2f(p.z); sw += bf2f(p.w);
  }
  float4 bp = *(const float4*)&b_pre[c];
  float s = stdv[r], m = muv[r];
  float4 o;
  o.x = (sx + bp.x) * s + m;
  o.y = (sy + bp.y) * s + m;
  o.z = (sz + bp.z) * s + m;
  o.w = (sw + bp.w) * s + m;
  *(float4*)&out[e0] = o;
}

// ---------------- per-row exact top-64 & top-512 via 32-pass radix bisection -------
__device__ __forceinline__ unsigned key_of(float f) {
  unsigned u = __float_as_uint(f);
  return (u & 0x80000000u) ? ~u : (u | 0x80000000u);
}
__device__ __forceinline__ float val_of(unsigned k) {
  unsigned u = (k & 0x80000000u) ? (k & 0x7FFFFFFFu) : ~k;
  return __uint_as_float(u);
}

__global__ __launch_bounds__(256) void topk_kernel(
    const float* __restrict__ pre, int r0,
    int* __restrict__ midx, float* __restrict__ mval,
    int* __restrict__ aidx, ushort* __restrict__ aval,
    int* __restrict__ fired)
{
  const int rl = blockIdx.x, t = threadIdx.x;
  const int r = r0 + rl;
  __shared__ unsigned keys[HID];
  __shared__ int tie64[TIE_CAP], tie512[TIE_CAP];
  __shared__ int cm, ca, c64, c512;

  const float4* src = (const float4*)(pre + (size_t)rl * HID);
  for (int i = t; i < HID / 4; i += 256) {
    float4 v = src[i];
    uint4 kk;
    kk.x = key_of(v.x); kk.y = key_of(v.y); kk.z = key_of(v.z); kk.w = key_of(v.w);
    ((uint4*)keys)[i] = kk;
  }
  if (t == 0) { cm = 0; ca = 0; c64 = 0; c512 = 0; }
  __syncthreads();

  unsigned T64 = 0, T512 = 0;
  for (int bit = 31; bit >= 0; --bit) {
    unsigned m64 = T64 | (1u << bit), m512 = T512 | (1u << bit);
    int n = 0;
    for (int i = t; i < HID; i += 256) {
      unsigned k = keys[i];
      n += (k >= m64) ? 1 : 0;
      n += (k >= m512) ? 0x10000 : 0;
    }
    n = block_sum_i(n);
    if ((n & 0xFFFF) >= KTOP) T64 = m64;
    if ((unsigned)(n >> 16) >= KAUX) T512 = m512;
  }

  for (int i = t; i < HID; i += 256) {
    unsigned k = keys[i];
    if (k > T512) {
      int p = atomicAdd(&ca, 1);
      float v = val_of(k);
      aidx[(size_t)r * KAUX + p] = i;
      aval[(size_t)r * KAUX + p] = f2bf(v > 0.f ? v : 0.f);
    } else if (k == T512) {
      int p = atomicAdd(&c512, 1);
      if (p < TIE_CAP) tie512[p] = i;
    }
    if (k > T64) {
      int p = atomicAdd(&cm, 1);
      float v = val_of(k);
      midx[(size_t)r * KTOP + p] = i;
      mval[(size_t)r * KTOP + p] = v > 0.f ? v : 0.f;
      if (v > 0.f) fired[i] = 1;
    } else if (k == T64) {
      int p = atomicAdd(&c64, 1);
      if (p < TIE_CAP) tie64[p] = i;
    }
  }
  __syncthreads();

  if (t == 0) {  // append lowest-index ties for main
    int have = cm, nt = c64 < TIE_CAP ? c64 : TIE_CAP, need = KTOP - have;
    float v = val_of(T64); float rv = v > 0.f ? v : 0.f;
    for (int q = 0; q < need; ++q) {
      int best = 0x7FFFFFFF, bi = -1;
      for (int u = 0; u < nt; ++u) if (tie64[u] < best) { best = tie64[u]; bi = u; }
      if (bi < 0) break;
      tie64[bi] = 0x7FFFFFFF;
      midx[(size_t)r * KTOP + have + q] = best;
      mval[(size_t)r * KTOP + have + q] = rv;
      if (v > 0.f) fired[best] = 1;
    }
  }
  if (t == 64) {  // append lowest-index ties for aux
    int have = ca, nt = c512 < TIE_CAP ? c512 : TIE_CAP, need = KAUX - have;
    float v = val_of(T512); float rv = v > 0.f ? v : 0.f;
    ushort rb = f2bf(rv);
    for (int q = 0; q < need; ++q) {
      int best = 0x7FFFFFFF, bi = -1;
      for (int u = 0; u < nt; ++u) if (tie512[u] < best) { best = tie512[u]; bi = u; }
      if (bi < 0) break;
      tie512[bi] = 0x7FFFFFFF;
      aidx[(size_t)r * KAUX + have + q] = best;
      aval[(size_t)r * KAUX + have + q] = rb;
    }
  }
}

// ---------------- stats / num_dead ----------------
__global__ __launch_bounds__(256) void stats_kernel(
    const int* __restrict__ fired, const int* __restrict__ sln, float* __restrict__ nd_out)
{
  int t = threadIdx.x, c = 0;
  for (int j = t; j < HID; j += 256) {
    int dead = (fired[j] == 0) ? 1 : 0;
    int stats = sln[j] * dead + 1;
    if ((float)stats > (2000.0f / 4096.0f)) c++;
  }
  c = block_sum_i(c);
  if (t == 0) nd_out[0] = (float)c;
}

// ---------------- scatter aux latents into dense bf16 matrix ----------------
__global__ __launch_bounds__(256) void scatter_aux(
    const int* __restrict__ aidx, const ushort* __restrict__ aval, ushort* __restrict__ A2)
{
  int g = blockIdx.x * 256 + threadIdx.x;
  int r = g >> 9;
  int j = aidx[g];
  A2[(size_t)r * HID + j] = aval[g];
}

// ---------------- main decode: sparse gather, f32 exact ----------------
__global__ __launch_bounds__(256) void decode_main(
    const int* __restrict__ midx, const float* __restrict__ mval,
    const float* __restrict__ wdec, const float* __restrict__ b_pre,
    const float* __restrict__ stdv, const float* __restrict__ muv,
    float* __restrict__ out)
{
  int r = blockIdx.x, t = threadIdx.x;
  __shared__ int sj[KTOP];
  __shared__ float sv[KTOP];
  if (t < KTOP) { sj[t] = midx[(size_t)r * KTOP + t]; sv[t] = mval[(size_t)r * KTOP + t]; }
  __syncthreads();
  float ax = 0.f, ay = 0.f, az = 0.f, aw = 0.f;
  for (int i = 0; i < KTOP; ++i) {
    float v = sv[i];
    const float4* wrow = (const float4*)(wdec + (size_t)sj[i] * IN_DIM);
    float4 wv = wrow[t];
    ax += v * wv.x; ay += v * wv.y; az += v * wv.z; aw += v * wv.w;
  }
  float4 bp = ((const float4*)b_pre)[t];
  float s = stdv[r], m = muv[r];
  float4 o;
  o.x = (ax + bp.x) * s + m;
  o.y = (ay + bp.y) * s + m;
  o.z = (az + bp.z) * s + m;
  o.w = (aw + bp.w) * s + m;
  ((float4*)(out + (size_t)r * IN_DIM))[t] = o;
}

__global__ void diag_kernel(float* p, float v) { p[0] = v; }

// ---------------- launch ----------------
extern "C" void kernel_launch(void* const* d_in, const int* in_sizes, int n_in,
                              void* d_out, int out_size, void* d_ws, size_t ws_size,
                              hipStream_t stream)
{
  const float* x     = (const float*)d_in[0];
  const float* w_enc = (const float*)d_in[1];
  const float* w_dec = (const float*)d_in[2];
  const float* b_enc = (const float*)d_in[3];
  const float* b_pre = (const float*)d_in[4];
  const int*   sln   = (const int*)d_in[5];

  float* out0 = (float*)d_out;                          // recons [4096][1024]
  float* out1 = out0 + (size_t)BATCH * IN_DIM;          // aux_recons
  float* out2 = out0 + 2 * (size_t)BATCH * IN_DIM;      // num_dead (as f32)

  char* ws = (char*)d_ws;
  size_t off = 0;
  auto take = [&](size_t bytes) { char* p = ws + off; off += (bytes + 255) & ~(size_t)255; return p; };

  // pre (half-batch f32, 128 MB) aliases A2 (full-batch bf16, 128 MB)
  float*  pre      = (float*)take((size_t)HALF_B * HID * 4);
  ushort* A2       = (ushort*)pre;
  ushort* wencT    = (ushort*)take((size_t)HID * IN_DIM * 2);
  ushort* wdecT    = (ushort*)take((size_t)HID * IN_DIM * 2);
  ushort* xh       = (ushort*)take((size_t)BATCH * IN_DIM * 2);
  ushort* part     = (ushort*)take((size_t)KSPLIT * BATCH * IN_DIM * 2);
  float*  mu       = (float*)take(BATCH * 4);
  float*  stdv     = (float*)take(BATCH * 4);
  int*    midx     = (int*)take((size_t)BATCH * KTOP * 4);
  float*  mval     = (float*)take((size_t)BATCH * KTOP * 4);
  int*    aidx     = (int*)take((size_t)BATCH * KAUX * 4);
  ushort* aval     = (ushort*)take((size_t)BATCH * KAUX * 2);
  int*    fired    = (int*)take(HID * 4);

  if (ws_size < off) {  // diagnostic: report actual ws_size through num_dead slot
    diag_kernel<<<1, 1, 0, stream>>>(out2, (float)ws_size);
    return;
  }

  ln_kernel<<<BATCH, 256, 0, stream>>>(x, b_pre, xh, mu, stdv);
  transpose_k<<<dim3(HID / 32, IN_DIM / 32), 256, 0, stream>>>(w_enc, wencT, IN_DIM, HID);
  transpose_k<<<dim3(IN_DIM / 32, HID / 32), 256, 0, stream>>>(w_dec, wdecT, HID, IN_DIM);
  hipMemsetAsync(fired, 0, HID * sizeof(int), stream);

  for (int half = 0; half < 2; ++half) {
    const ushort* Ah = xh + (size_t)half * HALF_B * IN_DIM;
    gemm128<0><<<dim3(HID / 128, HALF_B / 128, 1), 256, 0, stream>>>(
        Ah, wencT, pre, nullptr, b_enc, HALF_B, HID, IN_DIM, IN_DIM);
    topk_kernel<<<HALF_B, 256, 0, stream>>>(pre, half * HALF_B, midx, mval, aidx, aval, fired);
  }
  stats_kernel<<<1, 256, 0, stream>>>(fired, sln, out2);

  hipMemsetAsync(A2, 0, (size_t)BATCH * HID * 2, stream);   // pre dead now
  scatter_aux<<<(BATCH * KAUX) / 256, 256, 0, stream>>>(aidx, aval, A2);

  gemm128<1><<<dim3(IN_DIM / 128, BATCH / 128, KSPLIT), 256, 0, stream>>>(
      A2, wdecT, nullptr, part, nullptr, BATCH, IN_DIM, HID, HID / KSPLIT);
  reduce_dec<<<(BATCH * IN_DIM) / 1024, 256, 0, stream>>>(part, b_pre, stdv, mu, out1);

  decode_main<<<BATCH, 256, 0, stream>>>(midx, mval, w_dec, b_pre, stdv, mu, out0);
}

// Round 4
// 908.173 us; speedup vs baseline: 2.3239x; 1.5147x over previous
//
#include <hip/hip_runtime.h>

#define BATCH 4096
#define HALF_B 2048
#define IN_DIM 1024
#define HID 16384
#define KTOP 64
#define KAUX 512
#define KSPLIT 4
#define LN_EPS 1e-5f
#define TIE_CAP 768
#define NBIN 2048

typedef short s16x8 __attribute__((ext_vector_type(8)));
typedef float f32x4 __attribute__((ext_vector_type(4)));

__device__ __forceinline__ ushort f2bf(float f) {
  unsigned u = __float_as_uint(f);
  u += 0x7FFFu + ((u >> 16) & 1u);   // RNE
  return (ushort)(u >> 16);
}
__device__ __forceinline__ float bf2f(ushort h) {
  return __uint_as_float(((unsigned)h) << 16);
}

__device__ __forceinline__ void gl_lds16(const void* g, void* l) {
  __builtin_amdgcn_global_load_lds(
      (const __attribute__((address_space(1))) unsigned*)g,
      (__attribute__((address_space(3))) unsigned*)l, 16, 0, 0);
}

__device__ __forceinline__ float block_sum_f(float v) {
  __shared__ float redf[4];
  for (int o = 32; o > 0; o >>= 1) v += __shfl_down(v, o, 64);
  int lane = threadIdx.x & 63, w = threadIdx.x >> 6;
  if (lane == 0) redf[w] = v;
  __syncthreads();
  float t = (redf[0] + redf[1]) + (redf[2] + redf[3]);
  __syncthreads();
  return t;
}

__device__ __forceinline__ int block_sum_i(int v) {
  __shared__ int redi[4];
  for (int o = 32; o > 0; o >>= 1) v += __shfl_down(v, o, 64);
  int lane = threadIdx.x & 63, w = threadIdx.x >> 6;
  if (lane == 0) redi[w] = v;
  __syncthreads();
  int t = (redi[0] + redi[1]) + (redi[2] + redi[3]);
  __syncthreads();
  return t;
}

// ---------------- LayerNorm -> x_norm bf16, mu, std ----------------
__global__ __launch_bounds__(256) void ln_kernel(
    const float* __restrict__ x, const float* __restrict__ b_pre,
    ushort* __restrict__ xh, float* __restrict__ mu, float* __restrict__ stdv)
{
  int r = blockIdx.x, t = threadIdx.x;
  float4 v = ((const float4*)(x + (size_t)r * IN_DIM))[t];
  float s = (v.x + v.y) + (v.z + v.w);
  float mean = block_sum_f(s) * (1.0f / IN_DIM);
  float dx = v.x - mean, dy = v.y - mean, dz = v.z - mean, dw = v.w - mean;
  float ss = (dx*dx + dy*dy) + (dz*dz + dw*dw);
  float var = block_sum_f(ss) * (1.0f / (IN_DIM - 1));   // ddof = 1
  float sd = sqrtf(var);
  float inv = 1.0f / (sd + LN_EPS);
  float4 bp = ((const float4*)b_pre)[t];
  ushort h0 = f2bf(dx*inv - bp.x), h1 = f2bf(dy*inv - bp.y);
  ushort h2 = f2bf(dz*inv - bp.z), h3 = f2bf(dw*inv - bp.w);
  *(ushort4*)(xh + (size_t)r * IN_DIM + t * 4) = make_ushort4(h0, h1, h2, h3);
  if (t == 0) { mu[r] = mean; stdv[r] = sd; }
}

// ---------------- transpose f32 [R][C] -> bf16 [C][R] ----------------
__global__ __launch_bounds__(256) void transpose_k(
    const float* __restrict__ in, ushort* __restrict__ oh, int R, int C)
{
  __shared__ float tile[32][33];
  int c0 = blockIdx.x * 32, r0 = blockIdx.y * 32;
  int t = threadIdx.x;
  int col = t & 31, rbase = t >> 5;
  #pragma unroll
  for (int rep = 0; rep < 4; ++rep) {
    int rr = rbase + rep * 8;
    tile[rr][col] = in[(size_t)(r0 + rr) * C + c0 + col];
  }
  __syncthreads();
  int j = t & 31, ibase = t >> 5;
  #pragma unroll
  for (int rep = 0; rep < 4; ++rep) {
    int i = ibase + rep * 8;
    oh[(size_t)(c0 + i) * R + r0 + j] = f2bf(tile[j][i]);
  }
}

// ---------------- GEMM C = A @ B^T, bf16 MFMA, 128x128 tile, XCD swizzle ----------
// MODE 0: C f32 = acc + bias[n]                       (encoder)
// MODE 1: C bf16 partial (split-K via blockIdx.z)     (decoder)
template<int MODE>
__global__ __launch_bounds__(256) void gemm128(
    const ushort* __restrict__ A, const ushort* __restrict__ B,
    float* __restrict__ Cf, ushort* __restrict__ Cb,
    const float* __restrict__ bias, int M, int N, int K, int kchunk)
{
  __shared__ ushort lds[2 * 128 * 64];
  ushort* As = lds;
  ushort* Bs = lds + 128 * 64;

  // XCD-aware swizzle (valid: nwg % 8 == 0 for all our launches)
  const int gx = gridDim.x;
  const int nwg = gx * gridDim.y;
  const int flat = blockIdx.y * gx + blockIdx.x;
  const int cpx = nwg >> 3;
  const int sw = (flat & 7) * cpx + (flat >> 3);
  const int bn0 = (sw % gx) * 128, bm0 = (sw / gx) * 128;

  const int tid = threadIdx.x, w = tid >> 6, lane = tid & 63;
  const int wm = w >> 1, wn = w & 1;
  const int fr = lane & 15, fq = lane >> 4;
  const int srow = lane >> 3, scol = (lane & 7) * 8;
  const int kbeg = blockIdx.z * kchunk;

  f32x4 acc[4][4] = {};
  const int nk = kchunk >> 6;
  for (int kt = 0; kt < nk; ++kt) {
    const int k0 = kbeg + (kt << 6);
    __syncthreads();
    #pragma unroll
    for (int i = 0; i < 4; ++i) {
      int rr = (i * 4 + w) * 8 + srow;
      gl_lds16(A + (size_t)(bm0 + rr) * K + k0 + scol, &As[(i * 4 + w) * 512]);
      gl_lds16(B + (size_t)(bn0 + rr) * K + k0 + scol, &Bs[(i * 4 + w) * 512]);
    }
    __syncthreads();
    #pragma unroll
    for (int ks = 0; ks < 2; ++ks) {
      s16x8 ah[4], bh[4];
      #pragma unroll
      for (int i = 0; i < 4; ++i) {
        int ar = wm * 64 + i * 16 + fr;
        int br = wn * 64 + i * 16 + fr;
        int co = ks * 32 + fq * 8;
        ah[i] = *(const s16x8*)&As[ar * 64 + co];
        bh[i] = *(const s16x8*)&Bs[br * 64 + co];
      }
      #pragma unroll
      for (int mi = 0; mi < 4; ++mi)
        #pragma unroll
        for (int ni = 0; ni < 4; ++ni)
          acc[mi][ni] = __builtin_amdgcn_mfma_f32_16x16x32_bf16(ah[mi], bh[ni], acc[mi][ni], 0, 0, 0);
    }
  }
  #pragma unroll
  for (int mi = 0; mi < 4; ++mi) {
    int grow_b = bm0 + wm * 64 + mi * 16 + fq * 4;
    #pragma unroll
    for (int ni = 0; ni < 4; ++ni) {
      int gcol = bn0 + wn * 64 + ni * 16 + fr;
      #pragma unroll
      for (int q = 0; q < 4; ++q) {
        int grow = grow_b + q;
        if constexpr (MODE == 0) {
          Cf[(size_t)grow * N + gcol] = acc[mi][ni][q] + bias[gcol];
        } else {
          Cb[((size_t)blockIdx.z * M + grow) * N + gcol] = f2bf(acc[mi][ni][q]);
        }
      }
    }
  }
}

// ---------------- reduce split-K partials + decoder epilogue ----------------
__global__ __launch_bounds__(256) void reduce_dec(
    const ushort* __restrict__ P, const float* __restrict__ b_pre,
    const float* __restrict__ stdv, const float* __restrict__ muv,
    float* __restrict__ out)
{
  int gid = blockIdx.x * 256 + threadIdx.x;
  size_t e0 = (size_t)gid * 4;
  int r = (int)(e0 >> 10), c = (int)(e0 & 1023);
  float sx = 0.f, sy = 0.f, sz = 0.f, sw = 0.f;
  #pragma unroll
  for (int ks = 0; ks < KSPLIT; ++ks) {
    ushort4 p = *(const ushort4*)&P[(size_t)ks * BATCH * IN_DIM + e0];
    sx += bf2f(p.x); sy += bf2f(p.y); sz += bf2f(p.z); sw += bf2f(p.w);
  }
  float4 bp = *(const float4*)&b_pre[c];
  float s = stdv[r], m = muv[r];
  float4 o;
  o.x = (sx + bp.x) * s + m;
  o.y = (sy + bp.y) * s + m;
  o.z = (sz + bp.z) * s + m;
  o.w = (sw + bp.w) * s + m;
  *(float4*)&out[e0] = o;
}

// ---------------- top-k v2: register keys + two-level histogram select ------------
__device__ __forceinline__ unsigned key_of(float f) {
  unsigned u = __float_as_uint(f);
  return (u & 0x80000000u) ? ~u : (u | 0x80000000u);
}
__device__ __forceinline__ float val_of(unsigned k) {
  unsigned u = (k & 0x80000000u) ? (k & 0x7FFFFFFFu) : ~k;
  return __uint_as_float(u);
}

// Suffix-scan hist[NBIN] in place (hist[b] := #elements in bins >= b) and find,
// for K1 and K2, the boundary bin b with S[b] >= K && S[b+1] < K.
// res[0]=bin(K1), res[1]=S[bin+1](K1), res[2]=bin(K2), res[3]=S[bin+1](K2).
__device__ __forceinline__ void scan_find(int* hist, int t, int K1, int K2,
                                          int* res, int* wsum)
{
  int lane = t & 63, w = t >> 6;
  int h[8];
  #pragma unroll
  for (int j = 0; j < 8; ++j) h[j] = hist[t * 8 + j];
  int p = 0;
  #pragma unroll
  for (int j = 0; j < 8; ++j) p += h[j];
  int v = p;
  #pragma unroll
  for (int off = 1; off < 64; off <<= 1) {
    int o = __shfl_down(v, off, 64);
    if (lane + off < 64) v += o;
  }
  if (lane == 0) wsum[w] = v;
  __syncthreads();
  int above_w = 0;
  for (int ww = w + 1; ww < 4; ++ww) above_w += wsum[ww];
  int incl = __shfl(v, lane, 64);  // v already per-thread inclusive? no: recompute below
  // v at this lane = sum over lanes [lane..63] of p; add higher waves:
  incl = v + above_w;
  int E = incl - p;                // suffix strictly above this thread's bins
  int S[9];
  S[8] = E;
  #pragma unroll
  for (int j = 7; j >= 0; --j) S[j] = h[j] + S[j + 1];
  #pragma unroll
  for (int j = 0; j < 8; ++j) hist[t * 8 + j] = S[j];
  #pragma unroll
  for (int j = 0; j < 8; ++j) {
    if (S[j] >= K1 && S[j + 1] < K1) { res[0] = t * 8 + j; res[1] = S[j + 1]; }
    if (S[j] >= K2 && S[j + 1] < K2) { res[2] = t * 8 + j; res[3] = S[j + 1]; }
  }
  __syncthreads();
}

__global__ __launch_bounds__(256) void topk2_kernel(
    const float* __restrict__ pre, int r0,
    int* __restrict__ midx, float* __restrict__ mval,
    int* __restrict__ aidx, ushort* __restrict__ aval,
    int* __restrict__ fired)
{
  const int rl = blockIdx.x, t = threadIdx.x;
  const int r = r0 + rl;
  __shared__ int histA[NBIN];
  __shared__ int histB[NBIN];
  __shared__ int wsum[4];
  __shared__ int res[12];
  __shared__ int tkey64[TIE_CAP], tidx64[TIE_CAP];
  __shared__ int tkey512[TIE_CAP], tidx512[TIE_CAP];
  __shared__ int cm, ca, c64, c512;

  // 64 keys per thread in registers (statically indexed everywhere)
  unsigned key[64];
  const float4* src = (const float4*)(pre + (size_t)rl * HID);
  #pragma unroll
  for (int c = 0; c < 16; ++c) {
    float4 v = src[c * 256 + t];
    key[c * 4 + 0] = key_of(v.x); key[c * 4 + 1] = key_of(v.y);
    key[c * 4 + 2] = key_of(v.z); key[c * 4 + 3] = key_of(v.w);
  }
  #pragma unroll
  for (int j = 0; j < 8; ++j) histA[t * 8 + j] = 0;
  if (t == 0) { cm = 0; ca = 0; c64 = 0; c512 = 0; }
  __syncthreads();

  // level 1: bits [31:21]
  #pragma unroll
  for (int q = 0; q < 64; ++q) atomicAdd(&histA[key[q] >> 21], 1);
  __syncthreads();
  scan_find(histA, t, KTOP, KAUX, res, wsum);
  const int B64 = res[0], above64 = res[1], B512 = res[2], above512 = res[3];

  // level 2: bits [20:10] within each boundary bin
  #pragma unroll
  for (int j = 0; j < 8; ++j) { histA[t * 8 + j] = 0; histB[t * 8 + j] = 0; }
  __syncthreads();
  #pragma unroll
  for (int q = 0; q < 64; ++q) {
    unsigned b = key[q] >> 21, sub = (key[q] >> 10) & 2047u;
    if (b == (unsigned)B64)  atomicAdd(&histA[sub], 1);
    if (b == (unsigned)B512) atomicAdd(&histB[sub], 1);
  }
  __syncthreads();
  scan_find(histA, t, KTOP - above64,  KTOP - above64,  res + 4, wsum);
  scan_find(histB, t, KAUX - above512, KAUX - above512, res + 8, wsum);

  const unsigned T64  = ((unsigned)B64  << 21) | ((unsigned)res[4] << 10);
  const unsigned T512 = ((unsigned)B512 << 21) | ((unsigned)res[8] << 10);
  const unsigned H64 = T64 + 1024u, H512 = T512 + 1024u;

  // output scan over register keys
  #pragma unroll
  for (int c = 0; c < 16; ++c) {
    #pragma unroll
    for (int j = 0; j < 4; ++j) {
      unsigned k = key[c * 4 + j];
      int i = c * 1024 + t * 4 + j;
      if (k >= H512) {
        int p = atomicAdd(&ca, 1);
        float v = val_of(k);
        aidx[(size_t)r * KAUX + p] = i;
        aval[(size_t)r * KAUX + p] = f2bf(v > 0.f ? v : 0.f);
      } else if (k >= T512) {
        int p = atomicAdd(&c512, 1);
        if (p < TIE_CAP) { tkey512[p] = (int)k; tidx512[p] = i; }
      }
      if (k >= H64) {
        int p = atomicAdd(&cm, 1);
        float v = val_of(k);
        midx[(size_t)r * KTOP + p] = i;
        mval[(size_t)r * KTOP + p] = v > 0.f ? v : 0.f;
        if (v > 0.f) fired[i] = 1;
      } else if (k >= T64) {
        int p = atomicAdd(&c64, 1);
        if (p < TIE_CAP) { tkey64[p] = (int)k; tidx64[p] = i; }
      }
    }
  }
  __syncthreads();

  if (t == 0) {  // fill main from boundary bucket, lowest index first
    int have = cm, nt = c64 < TIE_CAP ? c64 : TIE_CAP, need = KTOP - have;
    for (int q = 0; q < need; ++q) {
      int best = 0x7FFFFFFF, bi = -1;
      for (int u = 0; u < nt; ++u) if (tidx64[u] < best) { best = tidx64[u]; bi = u; }
      if (bi < 0) break;
      float v = val_of((unsigned)tkey64[bi]);
      tidx64[bi] = 0x7FFFFFFF;
      midx[(size_t)r * KTOP + have + q] = best;
      mval[(size_t)r * KTOP + have + q] = v > 0.f ? v : 0.f;
      if (v > 0.f) fired[best] = 1;
    }
  }
  if (t == 64) {  // fill aux from boundary bucket, lowest index first
    int have = ca, nt = c512 < TIE_CAP ? c512 : TIE_CAP, need = KAUX - have;
    for (int q = 0; q < need; ++q) {
      int best = 0x7FFFFFFF, bi = -1;
      for (int u = 0; u < nt; ++u) if (tidx512[u] < best) { best = tidx512[u]; bi = u; }
      if (bi < 0) break;
      float v = val_of((unsigned)tkey512[bi]);
      tidx512[bi] = 0x7FFFFFFF;
      aidx[(size_t)r * KAUX + have + q] = best;
      aval[(size_t)r * KAUX + have + q] = f2bf(v > 0.f ? v : 0.f);
    }
  }
}

// ---------------- stats / num_dead ----------------
__global__ __launch_bounds__(256) void stats_kernel(
    const int* __restrict__ fired, const int* __restrict__ sln, float* __restrict__ nd_out)
{
  int t = threadIdx.x, c = 0;
  for (int j = t; j < HID; j += 256) {
    int dead = (fired[j] == 0) ? 1 : 0;
    int stats = sln[j] * dead + 1;
    if ((float)stats > (2000.0f / 4096.0f)) c++;
  }
  c = block_sum_i(c);
  if (t == 0) nd_out[0] = (float)c;
}

// ---------------- scatter aux latents into dense bf16 matrix ----------------
__global__ __launch_bounds__(256) void scatter_aux(
    const int* __restrict__ aidx, const ushort* __restrict__ aval, ushort* __restrict__ A2)
{
  int g = blockIdx.x * 256 + threadIdx.x;
  int r = g >> 9;
  int j = aidx[g];
  A2[(size_t)r * HID + j] = aval[g];
}

// ---------------- main decode: sparse gather, f32 exact ----------------
__global__ __launch_bounds__(256) void decode_main(
    const int* __restrict__ midx, const float* __restrict__ mval,
    const float* __restrict__ wdec, const float* __restrict__ b_pre,
    const float* __restrict__ stdv, const float* __restrict__ muv,
    float* __restrict__ out)
{
  int r = blockIdx.x, t = threadIdx.x;
  __shared__ int sj[KTOP];
  __shared__ float sv[KTOP];
  if (t < KTOP) { sj[t] = midx[(size_t)r * KTOP + t]; sv[t] = mval[(size_t)r * KTOP + t]; }
  __syncthreads();
  float ax = 0.f, ay = 0.f, az = 0.f, aw = 0.f;
  for (int i = 0; i < KTOP; ++i) {
    float v = sv[i];
    const float4* wrow = (const float4*)(wdec + (size_t)sj[i] * IN_DIM);
    float4 wv = wrow[t];
    ax += v * wv.x; ay += v * wv.y; az += v * wv.z; aw += v * wv.w;
  }
  float4 bp = ((const float4*)b_pre)[t];
  float s = stdv[r], m = muv[r];
  float4 o;
  o.x = (ax + bp.x) * s + m;
  o.y = (ay + bp.y) * s + m;
  o.z = (az + bp.z) * s + m;
  o.w = (aw + bp.w) * s + m;
  ((float4*)(out + (size_t)r * IN_DIM))[t] = o;
}

__global__ void diag_kernel(float* p, float v) { p[0] = v; }

// ---------------- launch ----------------
extern "C" void kernel_launch(void* const* d_in, const int* in_sizes, int n_in,
                              void* d_out, int out_size, void* d_ws, size_t ws_size,
                              hipStream_t stream)
{
  const float* x     = (const float*)d_in[0];
  const float* w_enc = (const float*)d_in[1];
  const float* w_dec = (const float*)d_in[2];
  const float* b_enc = (const float*)d_in[3];
  const float* b_pre = (const float*)d_in[4];
  const int*   sln   = (const int*)d_in[5];

  float* out0 = (float*)d_out;                          // recons [4096][1024]
  float* out1 = out0 + (size_t)BATCH * IN_DIM;          // aux_recons
  float* out2 = out0 + 2 * (size_t)BATCH * IN_DIM;      // num_dead (as f32)

  char* ws = (char*)d_ws;
  size_t off = 0;
  auto take = [&](size_t bytes) { char* p = ws + off; off += (bytes + 255) & ~(size_t)255; return p; };

  // pre (half-batch f32, 128 MB) aliases A2 (full-batch bf16, 128 MB)
  float*  pre      = (float*)take((size_t)HALF_B * HID * 4);
  ushort* A2       = (ushort*)pre;
  ushort* wencT    = (ushort*)take((size_t)HID * IN_DIM * 2);
  ushort* wdecT    = (ushort*)take((size_t)HID * IN_DIM * 2);
  ushort* xh       = (ushort*)take((size_t)BATCH * IN_DIM * 2);
  ushort* part     = (ushort*)take((size_t)KSPLIT * BATCH * IN_DIM * 2);
  float*  mu       = (float*)take(BATCH * 4);
  float*  stdv     = (float*)take(BATCH * 4);
  int*    midx     = (int*)take((size_t)BATCH * KTOP * 4);
  float*  mval     = (float*)take((size_t)BATCH * KTOP * 4);
  int*    aidx     = (int*)take((size_t)BATCH * KAUX * 4);
  ushort* aval     = (ushort*)take((size_t)BATCH * KAUX * 2);
  int*    fired    = (int*)take(HID * 4);

  if (ws_size < off) {  // diagnostic: report actual ws_size through num_dead slot
    diag_kernel<<<1, 1, 0, stream>>>(out2, (float)ws_size);
    return;
  }

  ln_kernel<<<BATCH, 256, 0, stream>>>(x, b_pre, xh, mu, stdv);
  transpose_k<<<dim3(HID / 32, IN_DIM / 32), 256, 0, stream>>>(w_enc, wencT, IN_DIM, HID);
  transpose_k<<<dim3(IN_DIM / 32, HID / 32), 256, 0, stream>>>(w_dec, wdecT, HID, IN_DIM);
  hipMemsetAsync(fired, 0, HID * sizeof(int), stream);

  for (int half = 0; half < 2; ++half) {
    const ushort* Ah = xh + (size_t)half * HALF_B * IN_DIM;
    gemm128<0><<<dim3(HID / 128, HALF_B / 128, 1), 256, 0, stream>>>(
        Ah, wencT, pre, nullptr, b_enc, HALF_B, HID, IN_DIM, IN_DIM);
    topk2_kernel<<<HALF_B, 256, 0, stream>>>(pre, half * HALF_B, midx, mval, aidx, aval, fired);
  }
  stats_kernel<<<1, 256, 0, stream>>>(fired, sln, out2);

  hipMemsetAsync(A2, 0, (size_t)BATCH * HID * 2, stream);   // pre dead now
  scatter_aux<<<(BATCH * KAUX) / 256, 256, 0, stream>>>(aidx, aval, A2);

  gemm128<1><<<dim3(IN_DIM / 128, BATCH / 128, KSPLIT), 256, 0, stream>>>(
      A2, wdecT, nullptr, part, nullptr, BATCH, IN_DIM, HID, HID / KSPLIT);
  reduce_dec<<<(BATCH * IN_DIM) / 1024, 256, 0, stream>>>(part, b_pre, stdv, mu, out1);

  decode_main<<<BATCH, 256, 0, stream>>>(midx, mval, w_dec, b_pre, stdv, mu, out0);
}

// Round 5
// 749.448 us; speedup vs baseline: 2.8161x; 1.2118x over previous
//
#include <hip/hip_runtime.h>

#define BATCH 4096
#define HALF_B 2048
#define IN_DIM 1024
#define HID 16384
#define KTOP 64
#define KAUX 512
#define KSPLIT 4
#define LN_EPS 1e-5f
#define TIE_CAP 768
#define NBIN 2048

typedef short s16x8 __attribute__((ext_vector_type(8)));
typedef float f32x4 __attribute__((ext_vector_type(4)));

__device__ __forceinline__ ushort f2bf(float f) {
  unsigned u = __float_as_uint(f);
  u += 0x7FFFu + ((u >> 16) & 1u);   // RNE
  return (ushort)(u >> 16);
}
__device__ __forceinline__ float bf2f(ushort h) {
  return __uint_as_float(((unsigned)h) << 16);
}

__device__ __forceinline__ void gl_lds16(const void* g, void* l) {
  __builtin_amdgcn_global_load_lds(
      (const __attribute__((address_space(1))) unsigned*)g,
      (__attribute__((address_space(3))) unsigned*)l, 16, 0, 0);
}

__device__ __forceinline__ float block_sum_f(float v) {
  __shared__ float redf[4];
  for (int o = 32; o > 0; o >>= 1) v += __shfl_down(v, o, 64);
  int lane = threadIdx.x & 63, w = threadIdx.x >> 6;
  if (lane == 0) redf[w] = v;
  __syncthreads();
  float t = (redf[0] + redf[1]) + (redf[2] + redf[3]);
  __syncthreads();
  return t;
}

__device__ __forceinline__ int block_sum_i(int v) {
  __shared__ int redi[4];
  for (int o = 32; o > 0; o >>= 1) v += __shfl_down(v, o, 64);
  int lane = threadIdx.x & 63, w = threadIdx.x >> 6;
  if (lane == 0) redi[w] = v;
  __syncthreads();
  int t = (redi[0] + redi[1]) + (redi[2] + redi[3]);
  __syncthreads();
  return t;
}

// ---------------- LayerNorm -> x_norm bf16, mu, std ----------------
__global__ __launch_bounds__(256) void ln_kernel(
    const float* __restrict__ x, const float* __restrict__ b_pre,
    ushort* __restrict__ xh, float* __restrict__ mu, float* __restrict__ stdv)
{
  int r = blockIdx.x, t = threadIdx.x;
  float4 v = ((const float4*)(x + (size_t)r * IN_DIM))[t];
  float s = (v.x + v.y) + (v.z + v.w);
  float mean = block_sum_f(s) * (1.0f / IN_DIM);
  float dx = v.x - mean, dy = v.y - mean, dz = v.z - mean, dw = v.w - mean;
  float ss = (dx*dx + dy*dy) + (dz*dz + dw*dw);
  float var = block_sum_f(ss) * (1.0f / (IN_DIM - 1));   // ddof = 1
  float sd = sqrtf(var);
  float inv = 1.0f / (sd + LN_EPS);
  float4 bp = ((const float4*)b_pre)[t];
  ushort h0 = f2bf(dx*inv - bp.x), h1 = f2bf(dy*inv - bp.y);
  ushort h2 = f2bf(dz*inv - bp.z), h3 = f2bf(dw*inv - bp.w);
  *(ushort4*)(xh + (size_t)r * IN_DIM + t * 4) = make_ushort4(h0, h1, h2, h3);
  if (t == 0) { mu[r] = mean; stdv[r] = sd; }
}

// ---------------- transpose f32 [R][C] -> bf16 [C][R] ----------------
__global__ __launch_bounds__(256) void transpose_k(
    const float* __restrict__ in, ushort* __restrict__ oh, int R, int C)
{
  __shared__ float tile[32][33];
  int c0 = blockIdx.x * 32, r0 = blockIdx.y * 32;
  int t = threadIdx.x;
  int col = t & 31, rbase = t >> 5;
  #pragma unroll
  for (int rep = 0; rep < 4; ++rep) {
    int rr = rbase + rep * 8;
    tile[rr][col] = in[(size_t)(r0 + rr) * C + c0 + col];
  }
  __syncthreads();
  int j = t & 31, ibase = t >> 5;
  #pragma unroll
  for (int rep = 0; rep < 4; ++rep) {
    int i = ibase + rep * 8;
    oh[(size_t)(c0 + i) * R + r0 + j] = f2bf(tile[j][i]);
  }
}

// ---------------- GEMM C = A @ B^T, 256x256 tile, 8 waves, 2-phase prefetch -------
// MODE 0: C f32 = acc + bias[n]                       (encoder)
// MODE 1: C bf16 partial (split-K via blockIdx.z)     (decoder)
template<int MODE>
__global__ __launch_bounds__(512, 2) void gemm256(
    const ushort* __restrict__ A, const ushort* __restrict__ B,
    float* __restrict__ Cf, ushort* __restrict__ Cb,
    const float* __restrict__ bias, int M, int N, int K, int kchunk)
{
  // [buf][A:256x64 | B:256x64] x2 buffers = 128 KiB
  __shared__ ushort lds[4 * 256 * 64];

  const int tid = threadIdx.x;
  const int w = tid >> 6, lane = tid & 63;
  const int fr = lane & 15, fq = lane >> 4;
  const int wm = w >> 2, wn = w & 3;

  // XCD-aware swizzle over the xy-plane (nwg % 8 == 0 in all launches here)
  const int gx = gridDim.x, nwg = gx * gridDim.y;
  const int flat = blockIdx.y * gx + blockIdx.x;
  const int cpx = nwg >> 3;
  const int sw = (flat & 7) * cpx + (flat >> 3);
  const int bn0 = (sw % gx) * 256, bm0 = (sw / gx) * 256;
  const int kbeg = blockIdx.z * kchunk;

  const int srow = tid >> 3, sslot = (tid & 7) * 8;

  f32x4 acc[8][4] = {};

  auto STAGE = [&](int b, int kt) {
    const int k0 = kbeg + (kt << 6);
    #pragma unroll
    for (int c = 0; c < 4; ++c) {
      // chunk id = c*512 + tid; row = id>>3 (= c*64 + srow), slot = (id&7)*8
      int row = c * 64 + srow;
      gl_lds16(A + (size_t)(bm0 + row) * K + k0 + sslot,
               &lds[b * 32768 + c * 4096 + w * 512]);
      gl_lds16(B + (size_t)(bn0 + row) * K + k0 + sslot,
               &lds[b * 32768 + 16384 + c * 4096 + w * 512]);
    }
  };

  const int nt = kchunk >> 6;
  int cur = 0;
  STAGE(0, 0);
  __syncthreads();

  for (int t = 0; t < nt; ++t) {
    if (t + 1 < nt) STAGE(cur ^ 1, t + 1);   // prefetch next K-tile (other buffer)
    const ushort* Ab = &lds[cur * 32768];
    const ushort* Bb = &lds[cur * 32768 + 16384];
    #pragma unroll
    for (int ks = 0; ks < 2; ++ks) {
      s16x8 af[8], bfr[4];
      #pragma unroll
      for (int mi = 0; mi < 8; ++mi)
        af[mi] = *(const s16x8*)&Ab[(wm * 128 + mi * 16 + fr) * 64 + ks * 32 + fq * 8];
      #pragma unroll
      for (int ni = 0; ni < 4; ++ni)
        bfr[ni] = *(const s16x8*)&Bb[(wn * 64 + ni * 16 + fr) * 64 + ks * 32 + fq * 8];
      #pragma unroll
      for (int mi = 0; mi < 8; ++mi)
        #pragma unroll
        for (int ni = 0; ni < 4; ++ni)
          acc[mi][ni] = __builtin_amdgcn_mfma_f32_16x16x32_bf16(af[mi], bfr[ni], acc[mi][ni], 0, 0, 0);
    }
    __syncthreads();   // drains vmcnt(0)+lgkmcnt(0): prefetched tile ready, reads done
    cur ^= 1;
  }

  #pragma unroll
  for (int mi = 0; mi < 8; ++mi) {
    int grow_b = bm0 + wm * 128 + mi * 16 + fq * 4;
    #pragma unroll
    for (int ni = 0; ni < 4; ++ni) {
      int gcol = bn0 + wn * 64 + ni * 16 + fr;
      #pragma unroll
      for (int q = 0; q < 4; ++q) {
        int grow = grow_b + q;
        if constexpr (MODE == 0) {
          Cf[(size_t)grow * N + gcol] = acc[mi][ni][q] + bias[gcol];
        } else {
          Cb[((size_t)blockIdx.z * M + grow) * N + gcol] = f2bf(acc[mi][ni][q]);
        }
      }
    }
  }
}

// ---------------- reduce split-K partials + decoder epilogue ----------------
__global__ __launch_bounds__(256) void reduce_dec(
    const ushort* __restrict__ P, const float* __restrict__ b_pre,
    const float* __restrict__ stdv, const float* __restrict__ muv,
    float* __restrict__ out)
{
  int gid = blockIdx.x * 256 + threadIdx.x;
  size_t e0 = (size_t)gid * 4;
  int r = (int)(e0 >> 10), c = (int)(e0 & 1023);
  float sx = 0.f, sy = 0.f, sz = 0.f, sw = 0.f;
  #pragma unroll
  for (int ks = 0; ks < KSPLIT; ++ks) {
    ushort4 p = *(const ushort4*)&P[(size_t)ks * BATCH * IN_DIM + e0];
    sx += bf2f(p.x); sy += bf2f(p.y); sz += bf2f(p.z); sw += bf2f(p.w);
  }
  float4 bp = *(const float4*)&b_pre[c];
  float s = stdv[r], m = muv[r];
  float4 o;
  o.x = (sx + bp.x) * s + m;
  o.y = (sy + bp.y) * s + m;
  o.z = (sz + bp.z) * s + m;
  o.w = (sw + bp.w) * s + m;
  *(float4*)&out[e0] = o;
}

// ---------------- top-k v2: register keys + two-level histogram select ------------
__device__ __forceinline__ unsigned key_of(float f) {
  unsigned u = __float_as_uint(f);
  return (u & 0x80000000u) ? ~u : (u | 0x80000000u);
}
__device__ __forceinline__ float val_of(unsigned k) {
  unsigned u = (k & 0x80000000u) ? (k & 0x7FFFFFFFu) : ~k;
  return __uint_as_float(u);
}

__device__ __forceinline__ void scan_find(int* hist, int t, int K1, int K2,
                                          int* res, int* wsum)
{
  int lane = t & 63, w = t >> 6;
  int h[8];
  #pragma unroll
  for (int j = 0; j < 8; ++j) h[j] = hist[t * 8 + j];
  int p = 0;
  #pragma unroll
  for (int j = 0; j < 8; ++j) p += h[j];
  int v = p;
  #pragma unroll
  for (int off = 1; off < 64; off <<= 1) {
    int o = __shfl_down(v, off, 64);
    if (lane + off < 64) v += o;
  }
  if (lane == 0) wsum[w] = v;
  __syncthreads();
  int above_w = 0;
  for (int ww = w + 1; ww < 4; ++ww) above_w += wsum[ww];
  int incl = v + above_w;
  int E = incl - p;                // suffix strictly above this thread's bins
  int S[9];
  S[8] = E;
  #pragma unroll
  for (int j = 7; j >= 0; --j) S[j] = h[j] + S[j + 1];
  #pragma unroll
  for (int j = 0; j < 8; ++j) hist[t * 8 + j] = S[j];
  #pragma unroll
  for (int j = 0; j < 8; ++j) {
    if (S[j] >= K1 && S[j + 1] < K1) { res[0] = t * 8 + j; res[1] = S[j + 1]; }
    if (S[j] >= K2 && S[j + 1] < K2) { res[2] = t * 8 + j; res[3] = S[j + 1]; }
  }
  __syncthreads();
}

__global__ __launch_bounds__(256) void topk2_kernel(
    const float* __restrict__ pre, int r0,
    int* __restrict__ midx, float* __restrict__ mval,
    int* __restrict__ aidx, ushort* __restrict__ aval,
    int* __restrict__ fired)
{
  const int rl = blockIdx.x, t = threadIdx.x;
  const int r = r0 + rl;
  __shared__ int histA[NBIN];
  __shared__ int histB[NBIN];
  __shared__ int wsum[4];
  __shared__ int res[12];
  __shared__ int tkey64[TIE_CAP], tidx64[TIE_CAP];
  __shared__ int tkey512[TIE_CAP], tidx512[TIE_CAP];
  __shared__ int cm, ca, c64, c512;

  unsigned key[64];
  const float4* src = (const float4*)(pre + (size_t)rl * HID);
  #pragma unroll
  for (int c = 0; c < 16; ++c) {
    float4 v = src[c * 256 + t];
    key[c * 4 + 0] = key_of(v.x); key[c * 4 + 1] = key_of(v.y);
    key[c * 4 + 2] = key_of(v.z); key[c * 4 + 3] = key_of(v.w);
  }
  #pragma unroll
  for (int j = 0; j < 8; ++j) histA[t * 8 + j] = 0;
  if (t == 0) { cm = 0; ca = 0; c64 = 0; c512 = 0; }
  __syncthreads();

  #pragma unroll
  for (int q = 0; q < 64; ++q) atomicAdd(&histA[key[q] >> 21], 1);
  __syncthreads();
  scan_find(histA, t, KTOP, KAUX, res, wsum);
  const int B64 = res[0], above64 = res[1], B512 = res[2], above512 = res[3];

  #pragma unroll
  for (int j = 0; j < 8; ++j) { histA[t * 8 + j] = 0; histB[t * 8 + j] = 0; }
  __syncthreads();
  #pragma unroll
  for (int q = 0; q < 64; ++q) {
    unsigned b = key[q] >> 21, sub = (key[q] >> 10) & 2047u;
    if (b == (unsigned)B64)  atomicAdd(&histA[sub], 1);
    if (b == (unsigned)B512) atomicAdd(&histB[sub], 1);
  }
  __syncthreads();
  scan_find(histA, t, KTOP - above64,  KTOP - above64,  res + 4, wsum);
  scan_find(histB, t, KAUX - above512, KAUX - above512, res + 8, wsum);

  const unsigned T64  = ((unsigned)B64  << 21) | ((unsigned)res[4] << 10);
  const unsigned T512 = ((unsigned)B512 << 21) | ((unsigned)res[8] << 10);
  const unsigned H64 = T64 + 1024u, H512 = T512 + 1024u;

  #pragma unroll
  for (int c = 0; c < 16; ++c) {
    #pragma unroll
    for (int j = 0; j < 4; ++j) {
      unsigned k = key[c * 4 + j];
      int i = c * 1024 + t * 4 + j;
      if (k >= H512) {
        int p = atomicAdd(&ca, 1);
        float v = val_of(k);
        aidx[(size_t)r * KAUX + p] = i;
        aval[(size_t)r * KAUX + p] = f2bf(v > 0.f ? v : 0.f);
      } else if (k >= T512) {
        int p = atomicAdd(&c512, 1);
        if (p < TIE_CAP) { tkey512[p] = (int)k; tidx512[p] = i; }
      }
      if (k >= H64) {
        int p = atomicAdd(&cm, 1);
        float v = val_of(k);
        midx[(size_t)r * KTOP + p] = i;
        mval[(size_t)r * KTOP + p] = v > 0.f ? v : 0.f;
        if (v > 0.f) fired[i] = 1;
      } else if (k >= T64) {
        int p = atomicAdd(&c64, 1);
        if (p < TIE_CAP) { tkey64[p] = (int)k; tidx64[p] = i; }
      }
    }
  }
  __syncthreads();

  if (t == 0) {
    int have = cm, nt = c64 < TIE_CAP ? c64 : TIE_CAP, need = KTOP - have;
    for (int q = 0; q < need; ++q) {
      int best = 0x7FFFFFFF, bi = -1;
      for (int u = 0; u < nt; ++u) if (tidx64[u] < best) { best = tidx64[u]; bi = u; }
      if (bi < 0) break;
      float v = val_of((unsigned)tkey64[bi]);
      tidx64[bi] = 0x7FFFFFFF;
      midx[(size_t)r * KTOP + have + q] = best;
      mval[(size_t)r * KTOP + have + q] = v > 0.f ? v : 0.f;
      if (v > 0.f) fired[best] = 1;
    }
  }
  if (t == 64) {
    int have = ca, nt = c512 < TIE_CAP ? c512 : TIE_CAP, need = KAUX - have;
    for (int q = 0; q < need; ++q) {
      int best = 0x7FFFFFFF, bi = -1;
      for (int u = 0; u < nt; ++u) if (tidx512[u] < best) { best = tidx512[u]; bi = u; }
      if (bi < 0) break;
      float v = val_of((unsigned)tkey512[bi]);
      tidx512[bi] = 0x7FFFFFFF;
      aidx[(size_t)r * KAUX + have + q] = best;
      aval[(size_t)r * KAUX + have + q] = f2bf(v > 0.f ? v : 0.f);
    }
  }
}

// ---------------- stats / num_dead ----------------
__global__ __launch_bounds__(256) void stats_kernel(
    const int* __restrict__ fired, const int* __restrict__ sln, float* __restrict__ nd_out)
{
  int t = threadIdx.x, c = 0;
  for (int j = t; j < HID; j += 256) {
    int dead = (fired[j] == 0) ? 1 : 0;
    int stats = sln[j] * dead + 1;
    if ((float)stats > (2000.0f / 4096.0f)) c++;
  }
  c = block_sum_i(c);
  if (t == 0) nd_out[0] = (float)c;
}

// ---------------- scatter aux latents into dense bf16 matrix ----------------
__global__ __launch_bounds__(256) void scatter_aux(
    const int* __restrict__ aidx, const ushort* __restrict__ aval, ushort* __restrict__ A2)
{
  int g = blockIdx.x * 256 + threadIdx.x;
  int r = g >> 9;
  int j = aidx[g];
  A2[(size_t)r * HID + j] = aval[g];
}

// ---------------- main decode: sparse gather, f32 exact ----------------
__global__ __launch_bounds__(256) void decode_main(
    const int* __restrict__ midx, const float* __restrict__ mval,
    const float* __restrict__ wdec, const float* __restrict__ b_pre,
    const float* __restrict__ stdv, const float* __restrict__ muv,
    float* __restrict__ out)
{
  int r = blockIdx.x, t = threadIdx.x;
  __shared__ int sj[KTOP];
  __shared__ float sv[KTOP];
  if (t < KTOP) { sj[t] = midx[(size_t)r * KTOP + t]; sv[t] = mval[(size_t)r * KTOP + t]; }
  __syncthreads();
  float ax = 0.f, ay = 0.f, az = 0.f, aw = 0.f;
  for (int i = 0; i < KTOP; ++i) {
    float v = sv[i];
    const float4* wrow = (const float4*)(wdec + (size_t)sj[i] * IN_DIM);
    float4 wv = wrow[t];
    ax += v * wv.x; ay += v * wv.y; az += v * wv.z; aw += v * wv.w;
  }
  float4 bp = ((const float4*)b_pre)[t];
  float s = stdv[r], m = muv[r];
  float4 o;
  o.x = (ax + bp.x) * s + m;
  o.y = (ay + bp.y) * s + m;
  o.z = (az + bp.z) * s + m;
  o.w = (aw + bp.w) * s + m;
  ((float4*)(out + (size_t)r * IN_DIM))[t] = o;
}

__global__ void diag_kernel(float* p, float v) { p[0] = v; }

// ---------------- launch ----------------
extern "C" void kernel_launch(void* const* d_in, const int* in_sizes, int n_in,
                              void* d_out, int out_size, void* d_ws, size_t ws_size,
                              hipStream_t stream)
{
  const float* x     = (const float*)d_in[0];
  const float* w_enc = (const float*)d_in[1];
  const float* w_dec = (const float*)d_in[2];
  const float* b_enc = (const float*)d_in[3];
  const float* b_pre = (const float*)d_in[4];
  const int*   sln   = (const int*)d_in[5];

  float* out0 = (float*)d_out;                          // recons [4096][1024]
  float* out1 = out0 + (size_t)BATCH * IN_DIM;          // aux_recons
  float* out2 = out0 + 2 * (size_t)BATCH * IN_DIM;      // num_dead (as f32)

  char* ws = (char*)d_ws;
  size_t off = 0;
  auto take = [&](size_t bytes) { char* p = ws + off; off += (bytes + 255) & ~(size_t)255; return p; };

  // pre (half-batch f32, 128 MB) aliases A2 (full-batch bf16, 128 MB)
  float*  pre      = (float*)take((size_t)HALF_B * HID * 4);
  ushort* A2       = (ushort*)pre;
  ushort* wencT    = (ushort*)take((size_t)HID * IN_DIM * 2);
  ushort* wdecT    = (ushort*)take((size_t)HID * IN_DIM * 2);
  ushort* xh       = (ushort*)take((size_t)BATCH * IN_DIM * 2);
  ushort* part     = (ushort*)take((size_t)KSPLIT * BATCH * IN_DIM * 2);
  float*  mu       = (float*)take(BATCH * 4);
  float*  stdv     = (float*)take(BATCH * 4);
  int*    midx     = (int*)take((size_t)BATCH * KTOP * 4);
  float*  mval     = (float*)take((size_t)BATCH * KTOP * 4);
  int*    aidx     = (int*)take((size_t)BATCH * KAUX * 4);
  ushort* aval     = (ushort*)take((size_t)BATCH * KAUX * 2);
  int*    fired    = (int*)take(HID * 4);

  if (ws_size < off) {  // diagnostic: report actual ws_size through num_dead slot
    diag_kernel<<<1, 1, 0, stream>>>(out2, (float)ws_size);
    return;
  }

  ln_kernel<<<BATCH, 256, 0, stream>>>(x, b_pre, xh, mu, stdv);
  transpose_k<<<dim3(HID / 32, IN_DIM / 32), 256, 0, stream>>>(w_enc, wencT, IN_DIM, HID);
  transpose_k<<<dim3(IN_DIM / 32, HID / 32), 256, 0, stream>>>(w_dec, wdecT, HID, IN_DIM);
  hipMemsetAsync(fired, 0, HID * sizeof(int), stream);

  for (int half = 0; half < 2; ++half) {
    const ushort* Ah = xh + (size_t)half * HALF_B * IN_DIM;
    gemm256<0><<<dim3(HID / 256, HALF_B / 256, 1), 512, 0, stream>>>(
        Ah, wencT, pre, nullptr, b_enc, HALF_B, HID, IN_DIM, IN_DIM);
    topk2_kernel<<<HALF_B, 256, 0, stream>>>(pre, half * HALF_B, midx, mval, aidx, aval, fired);
  }
  stats_kernel<<<1, 256, 0, stream>>>(fired, sln, out2);

  hipMemsetAsync(A2, 0, (size_t)BATCH * HID * 2, stream);   // pre dead now
  scatter_aux<<<(BATCH * KAUX) / 256, 256, 0, stream>>>(aidx, aval, A2);

  gemm256<1><<<dim3(IN_DIM / 256, BATCH / 256, KSPLIT), 512, 0, stream>>>(
      A2, wdecT, nullptr, part, nullptr, BATCH, IN_DIM, HID, HID / KSPLIT);
  reduce_dec<<<(BATCH * IN_DIM) / 1024, 256, 0, stream>>>(part, b_pre, stdv, mu, out1);

  decode_main<<<BATCH, 256, 0, stream>>>(midx, mval, w_dec, b_pre, stdv, mu, out0);
}

// Round 6
// 737.489 us; speedup vs baseline: 2.8618x; 1.0162x over previous
//
#include <hip/hip_runtime.h>

#define BATCH 4096
#define HALF_B 2048
#define IN_DIM 1024
#define HID 16384
#define KTOP 64
#define KAUX 512
#define KSPLIT 4
#define LN_EPS 1e-5f
#define TIE_CAP 768
#define NBIN 2048

typedef short s16x8 __attribute__((ext_vector_type(8)));
typedef float f32x4 __attribute__((ext_vector_type(4)));

__device__ __forceinline__ ushort f2bf(float f) {
  unsigned u = __float_as_uint(f);
  u += 0x7FFFu + ((u >> 16) & 1u);   // RNE
  return (ushort)(u >> 16);
}
__device__ __forceinline__ float bf2f(ushort h) {
  return __uint_as_float(((unsigned)h) << 16);
}

__device__ __forceinline__ void gl_lds16(const void* g, void* l) {
  __builtin_amdgcn_global_load_lds(
      (const __attribute__((address_space(1))) unsigned*)g,
      (__attribute__((address_space(3))) unsigned*)l, 16, 0, 0);
}

__device__ __forceinline__ float block_sum_f(float v) {
  __shared__ float redf[4];
  for (int o = 32; o > 0; o >>= 1) v += __shfl_down(v, o, 64);
  int lane = threadIdx.x & 63, w = threadIdx.x >> 6;
  if (lane == 0) redf[w] = v;
  __syncthreads();
  float t = (redf[0] + redf[1]) + (redf[2] + redf[3]);
  __syncthreads();
  return t;
}

__device__ __forceinline__ int block_sum_i(int v) {
  __shared__ int redi[4];
  for (int o = 32; o > 0; o >>= 1) v += __shfl_down(v, o, 64);
  int lane = threadIdx.x & 63, w = threadIdx.x >> 6;
  if (lane == 0) redi[w] = v;
  __syncthreads();
  int t = (redi[0] + redi[1]) + (redi[2] + redi[3]);
  __syncthreads();
  return t;
}

// ---------------- LayerNorm -> x_norm bf16, mu, std ----------------
__global__ __launch_bounds__(256) void ln_kernel(
    const float* __restrict__ x, const float* __restrict__ b_pre,
    ushort* __restrict__ xh, float* __restrict__ mu, float* __restrict__ stdv)
{
  int r = blockIdx.x, t = threadIdx.x;
  float4 v = ((const float4*)(x + (size_t)r * IN_DIM))[t];
  float s = (v.x + v.y) + (v.z + v.w);
  float mean = block_sum_f(s) * (1.0f / IN_DIM);
  float dx = v.x - mean, dy = v.y - mean, dz = v.z - mean, dw = v.w - mean;
  float ss = (dx*dx + dy*dy) + (dz*dz + dw*dw);
  float var = block_sum_f(ss) * (1.0f / (IN_DIM - 1));   // ddof = 1
  float sd = sqrtf(var);
  float inv = 1.0f / (sd + LN_EPS);
  float4 bp = ((const float4*)b_pre)[t];
  ushort h0 = f2bf(dx*inv - bp.x), h1 = f2bf(dy*inv - bp.y);
  ushort h2 = f2bf(dz*inv - bp.z), h3 = f2bf(dw*inv - bp.w);
  *(ushort4*)(xh + (size_t)r * IN_DIM + t * 4) = make_ushort4(h0, h1, h2, h3);
  if (t == 0) { mu[r] = mean; stdv[r] = sd; }
}

// ---------------- transpose f32 [R][C] -> bf16 [C][R] ----------------
__global__ __launch_bounds__(256) void transpose_k(
    const float* __restrict__ in, ushort* __restrict__ oh, int R, int C)
{
  __shared__ float tile[32][33];
  int c0 = blockIdx.x * 32, r0 = blockIdx.y * 32;
  int t = threadIdx.x;
  int col = t & 31, rbase = t >> 5;
  #pragma unroll
  for (int rep = 0; rep < 4; ++rep) {
    int rr = rbase + rep * 8;
    tile[rr][col] = in[(size_t)(r0 + rr) * C + c0 + col];
  }
  __syncthreads();
  int j = t & 31, ibase = t >> 5;
  #pragma unroll
  for (int rep = 0; rep < 4; ++rep) {
    int i = ibase + rep * 8;
    oh[(size_t)(c0 + i) * R + r0 + j] = f2bf(tile[j][i]);
  }
}

// ---------------- GEMM C = A @ B^T, 256x256 tile, counted-vmcnt + T2 swizzle ------
// LDS: 2 buf x (A 256x64 + B 256x64) bf16 = 128 KiB.
// Swizzle (both-sides involution, rule #21): 16B-slot s of row r holds global
// col-slot s^(r&7); ds_read uses the same XOR. gload_lds dest stays linear.
// MODE 0: C f32 = acc + bias[n]                       (encoder)
// MODE 1: C bf16 partial (split-K via blockIdx.z)     (decoder)
template<int MODE>
__global__ __launch_bounds__(512, 2) void gemm256(
    const ushort* __restrict__ A, const ushort* __restrict__ B,
    float* __restrict__ Cf, ushort* __restrict__ Cb,
    const float* __restrict__ bias, int M, int N, int K, int kchunk)
{
  __shared__ ushort lds[2 * 2 * 256 * 64];

  const int tid = threadIdx.x;
  const int w = tid >> 6, lane = tid & 63;
  const int fr = lane & 15, fq = lane >> 4;
  const int wm = w >> 2, wn = w & 3;
  const int axr = fr & 7;                      // read-side swizzle key

  // XCD-aware swizzle over the xy-plane (nwg % 8 == 0 in all launches here)
  const int gx = gridDim.x, nwg = gx * gridDim.y;
  const int flat = blockIdx.y * gx + blockIdx.x;
  const int cpx = nwg >> 3;
  const int sw = (flat & 7) * cpx + (flat >> 3);
  const int bn0 = (sw % gx) * 256, bm0 = (sw / gx) * 256;
  const int kbeg = blockIdx.z * kchunk;

  const int srow = tid >> 3;                   // row within 64-row group
  const int sslot = tid & 7;                   // dest 16B slot

  f32x4 acc[8][4] = {};

  auto STAGE = [&](int kt) {
    const int b = kt & 1;
    const int k0 = kbeg + (kt << 6);
    #pragma unroll
    for (int c = 0; c < 4; ++c) {
      int row = c * 64 + srow;
      int gcol = (sslot ^ (row & 7)) * 8;      // pre-swizzled global source
      gl_lds16(A + (size_t)(bm0 + row) * K + k0 + gcol,
               &lds[b * 32768 + row * 64 + sslot * 8]);
      gl_lds16(B + (size_t)(bn0 + row) * K + k0 + gcol,
               &lds[b * 32768 + 16384 + row * 64 + sslot * 8]);
    }
  };

  const int nt = kchunk >> 6;   // >= 16 in all launches
  STAGE(0);
  for (int t = 0; t < nt; ++t) {
    if (t + 1 < nt) STAGE(t + 1);              // 8 loads -> in flight across MFMA
    if (t + 1 < nt) {
      asm volatile("s_waitcnt vmcnt(8)" ::: "memory");   // STAGE(t) arrived
    } else {
      asm volatile("s_waitcnt vmcnt(0)" ::: "memory");   // final drain
    }
    __builtin_amdgcn_s_barrier();
    asm volatile("" ::: "memory");

    const ushort* Ab = &lds[(t & 1) * 32768];
    const ushort* Bb = Ab + 16384;
    #pragma unroll
    for (int ks = 0; ks < 2; ++ks) {
      s16x8 af[8], bfr[4];
      #pragma unroll
      for (int mi = 0; mi < 8; ++mi)
        af[mi] = *(const s16x8*)&Ab[(wm * 128 + mi * 16 + fr) * 64 + (((ks * 4 + fq) ^ axr) * 8)];
      #pragma unroll
      for (int ni = 0; ni < 4; ++ni)
        bfr[ni] = *(const s16x8*)&Bb[(wn * 64 + ni * 16 + fr) * 64 + (((ks * 4 + fq) ^ axr) * 8)];
      __builtin_amdgcn_s_setprio(1);
      #pragma unroll
      for (int mi = 0; mi < 8; ++mi)
        #pragma unroll
        for (int ni = 0; ni < 4; ++ni)
          acc[mi][ni] = __builtin_amdgcn_mfma_f32_16x16x32_bf16(af[mi], bfr[ni], acc[mi][ni], 0, 0, 0);
      __builtin_amdgcn_s_setprio(0);
    }
    __builtin_amdgcn_s_barrier();              // all reads of buf done before re-stage
    asm volatile("" ::: "memory");
  }

  #pragma unroll
  for (int mi = 0; mi < 8; ++mi) {
    int grow_b = bm0 + wm * 128 + mi * 16 + fq * 4;
    #pragma unroll
    for (int ni = 0; ni < 4; ++ni) {
      int gcol = bn0 + wn * 64 + ni * 16 + fr;
      #pragma unroll
      for (int q = 0; q < 4; ++q) {
        int grow = grow_b + q;
        if constexpr (MODE == 0) {
          Cf[(size_t)grow * N + gcol] = acc[mi][ni][q] + bias[gcol];
        } else {
          Cb[((size_t)blockIdx.z * M + grow) * N + gcol] = f2bf(acc[mi][ni][q]);
        }
      }
    }
  }
}

// ---------------- reduce split-K partials + decoder epilogue ----------------
__global__ __launch_bounds__(256) void reduce_dec(
    const ushort* __restrict__ P, const float* __restrict__ b_pre,
    const float* __restrict__ stdv, const float* __restrict__ muv,
    float* __restrict__ out)
{
  int gid = blockIdx.x * 256 + threadIdx.x;
  size_t e0 = (size_t)gid * 4;
  int r = (int)(e0 >> 10), c = (int)(e0 & 1023);
  float sx = 0.f, sy = 0.f, sz = 0.f, sw = 0.f;
  #pragma unroll
  for (int ks = 0; ks < KSPLIT; ++ks) {
    ushort4 p = *(const ushort4*)&P[(size_t)ks * BATCH * IN_DIM + e0];
    sx += bf2f(p.x); sy += bf2f(p.y); sz += bf2f(p.z); sw += bf2f(p.w);
  }
  float4 bp = *(const float4*)&b_pre[c];
  float s = stdv[r], m = muv[r];
  float4 o;
  o.x = (sx + bp.x) * s + m;
  o.y = (sy + bp.y) * s + m;
  o.z = (sz + bp.z) * s + m;
  o.w = (sw + bp.w) * s + m;
  *(float4*)&out[e0] = o;
}

// ---------------- top-k v2: register keys + two-level histogram select ------------
__device__ __forceinline__ unsigned key_of(float f) {
  unsigned u = __float_as_uint(f);
  return (u & 0x80000000u) ? ~u : (u | 0x80000000u);
}
__device__ __forceinline__ float val_of(unsigned k) {
  unsigned u = (k & 0x80000000u) ? (k & 0x7FFFFFFFu) : ~k;
  return __uint_as_float(u);
}

__device__ __forceinline__ void scan_find(int* hist, int t, int K1, int K2,
                                          int* res, int* wsum)
{
  int lane = t & 63, w = t >> 6;
  int h[8];
  #pragma unroll
  for (int j = 0; j < 8; ++j) h[j] = hist[t * 8 + j];
  int p = 0;
  #pragma unroll
  for (int j = 0; j < 8; ++j) p += h[j];
  int v = p;
  #pragma unroll
  for (int off = 1; off < 64; off <<= 1) {
    int o = __shfl_down(v, off, 64);
    if (lane + off < 64) v += o;
  }
  if (lane == 0) wsum[w] = v;
  __syncthreads();
  int above_w = 0;
  for (int ww = w + 1; ww < 4; ++ww) above_w += wsum[ww];
  int incl = v + above_w;
  int E = incl - p;                // suffix strictly above this thread's bins
  int S[9];
  S[8] = E;
  #pragma unroll
  for (int j = 7; j >= 0; --j) S[j] = h[j] + S[j + 1];
  #pragma unroll
  for (int j = 0; j < 8; ++j) hist[t * 8 + j] = S[j];
  #pragma unroll
  for (int j = 0; j < 8; ++j) {
    if (S[j] >= K1 && S[j + 1] < K1) { res[0] = t * 8 + j; res[1] = S[j + 1]; }
    if (S[j] >= K2 && S[j + 1] < K2) { res[2] = t * 8 + j; res[3] = S[j + 1]; }
  }
  __syncthreads();
}

__global__ __launch_bounds__(256) void topk2_kernel(
    const float* __restrict__ pre, int r0,
    int* __restrict__ midx, float* __restrict__ mval,
    int* __restrict__ aidx, ushort* __restrict__ aval,
    int* __restrict__ fired)
{
  const int rl = blockIdx.x, t = threadIdx.x;
  const int r = r0 + rl;
  __shared__ int histA[NBIN];
  __shared__ int histB[NBIN];
  __shared__ int wsum[4];
  __shared__ int res[12];
  __shared__ int tkey64[TIE_CAP], tidx64[TIE_CAP];
  __shared__ int tkey512[TIE_CAP], tidx512[TIE_CAP];
  __shared__ int cm, ca, c64, c512;

  unsigned key[64];
  const float4* src = (const float4*)(pre + (size_t)rl * HID);
  #pragma unroll
  for (int c = 0; c < 16; ++c) {
    float4 v = src[c * 256 + t];
    key[c * 4 + 0] = key_of(v.x); key[c * 4 + 1] = key_of(v.y);
    key[c * 4 + 2] = key_of(v.z); key[c * 4 + 3] = key_of(v.w);
  }
  #pragma unroll
  for (int j = 0; j < 8; ++j) histA[t * 8 + j] = 0;
  if (t == 0) { cm = 0; ca = 0; c64 = 0; c512 = 0; }
  __syncthreads();

  #pragma unroll
  for (int q = 0; q < 64; ++q) atomicAdd(&histA[key[q] >> 21], 1);
  __syncthreads();
  scan_find(histA, t, KTOP, KAUX, res, wsum);
  const int B64 = res[0], above64 = res[1], B512 = res[2], above512 = res[3];

  #pragma unroll
  for (int j = 0; j < 8; ++j) { histA[t * 8 + j] = 0; histB[t * 8 + j] = 0; }
  __syncthreads();
  #pragma unroll
  for (int q = 0; q < 64; ++q) {
    unsigned b = key[q] >> 21, sub = (key[q] >> 10) & 2047u;
    if (b == (unsigned)B64)  atomicAdd(&histA[sub], 1);
    if (b == (unsigned)B512) atomicAdd(&histB[sub], 1);
  }
  __syncthreads();
  scan_find(histA, t, KTOP - above64,  KTOP - above64,  res + 4, wsum);
  scan_find(histB, t, KAUX - above512, KAUX - above512, res + 8, wsum);

  const unsigned T64  = ((unsigned)B64  << 21) | ((unsigned)res[4] << 10);
  const unsigned T512 = ((unsigned)B512 << 21) | ((unsigned)res[8] << 10);
  const unsigned H64 = T64 + 1024u, H512 = T512 + 1024u;

  #pragma unroll
  for (int c = 0; c < 16; ++c) {
    #pragma unroll
    for (int j = 0; j < 4; ++j) {
      unsigned k = key[c * 4 + j];
      int i = c * 1024 + t * 4 + j;
      if (k >= H512) {
        int p = atomicAdd(&ca, 1);
        float v = val_of(k);
        aidx[(size_t)r * KAUX + p] = i;
        aval[(size_t)r * KAUX + p] = f2bf(v > 0.f ? v : 0.f);
      } else if (k >= T512) {
        int p = atomicAdd(&c512, 1);
        if (p < TIE_CAP) { tkey512[p] = (int)k; tidx512[p] = i; }
      }
      if (k >= H64) {
        int p = atomicAdd(&cm, 1);
        float v = val_of(k);
        midx[(size_t)r * KTOP + p] = i;
        mval[(size_t)r * KTOP + p] = v > 0.f ? v : 0.f;
        if (v > 0.f) fired[i] = 1;
      } else if (k >= T64) {
        int p = atomicAdd(&c64, 1);
        if (p < TIE_CAP) { tkey64[p] = (int)k; tidx64[p] = i; }
      }
    }
  }
  __syncthreads();

  if (t == 0) {
    int have = cm, nt = c64 < TIE_CAP ? c64 : TIE_CAP, need = KTOP - have;
    for (int q = 0; q < need; ++q) {
      int best = 0x7FFFFFFF, bi = -1;
      for (int u = 0; u < nt; ++u) if (tidx64[u] < best) { best = tidx64[u]; bi = u; }
      if (bi < 0) break;
      float v = val_of((unsigned)tkey64[bi]);
      tidx64[bi] = 0x7FFFFFFF;
      midx[(size_t)r * KTOP + have + q] = best;
      mval[(size_t)r * KTOP + have + q] = v > 0.f ? v : 0.f;
      if (v > 0.f) fired[best] = 1;
    }
  }
  if (t == 64) {
    int have = ca, nt = c512 < TIE_CAP ? c512 : TIE_CAP, need = KAUX - have;
    for (int q = 0; q < need; ++q) {
      int best = 0x7FFFFFFF, bi = -1;
      for (int u = 0; u < nt; ++u) if (tidx512[u] < best) { best = tidx512[u]; bi = u; }
      if (bi < 0) break;
      float v = val_of((unsigned)tkey512[bi]);
      tidx512[bi] = 0x7FFFFFFF;
      aidx[(size_t)r * KAUX + have + q] = best;
      aval[(size_t)r * KAUX + have + q] = f2bf(v > 0.f ? v : 0.f);
    }
  }
}

// ---------------- stats / num_dead ----------------
__global__ __launch_bounds__(256) void stats_kernel(
    const int* __restrict__ fired, const int* __restrict__ sln, float* __restrict__ nd_out)
{
  int t = threadIdx.x, c = 0;
  for (int j = t; j < HID; j += 256) {
    int dead = (fired[j] == 0) ? 1 : 0;
    int stats = sln[j] * dead + 1;
    if ((float)stats > (2000.0f / 4096.0f)) c++;
  }
  c = block_sum_i(c);
  if (t == 0) nd_out[0] = (float)c;
}

// ---------------- scatter aux latents into dense bf16 matrix ----------------
__global__ __launch_bounds__(256) void scatter_aux(
    const int* __restrict__ aidx, const ushort* __restrict__ aval, ushort* __restrict__ A2)
{
  int g = blockIdx.x * 256 + threadIdx.x;
  int r = g >> 9;
  int j = aidx[g];
  A2[(size_t)r * HID + j] = aval[g];
}

// ---------------- main decode: sparse gather, f32 exact ----------------
__global__ __launch_bounds__(256) void decode_main(
    const int* __restrict__ midx, const float* __restrict__ mval,
    const float* __restrict__ wdec, const float* __restrict__ b_pre,
    const float* __restrict__ stdv, const float* __restrict__ muv,
    float* __restrict__ out)
{
  int r = blockIdx.x, t = threadIdx.x;
  __shared__ int sj[KTOP];
  __shared__ float sv[KTOP];
  if (t < KTOP) { sj[t] = midx[(size_t)r * KTOP + t]; sv[t] = mval[(size_t)r * KTOP + t]; }
  __syncthreads();
  float ax = 0.f, ay = 0.f, az = 0.f, aw = 0.f;
  for (int i = 0; i < KTOP; ++i) {
    float v = sv[i];
    const float4* wrow = (const float4*)(wdec + (size_t)sj[i] * IN_DIM);
    float4 wv = wrow[t];
    ax += v * wv.x; ay += v * wv.y; az += v * wv.z; aw += v * wv.w;
  }
  float4 bp = ((const float4*)b_pre)[t];
  float s = stdv[r], m = muv[r];
  float4 o;
  o.x = (ax + bp.x) * s + m;
  o.y = (ay + bp.y) * s + m;
  o.z = (az + bp.z) * s + m;
  o.w = (aw + bp.w) * s + m;
  ((float4*)(out + (size_t)r * IN_DIM))[t] = o;
}

__global__ void diag_kernel(float* p, float v) { p[0] = v; }

// ---------------- launch ----------------
extern "C" void kernel_launch(void* const* d_in, const int* in_sizes, int n_in,
                              void* d_out, int out_size, void* d_ws, size_t ws_size,
                              hipStream_t stream)
{
  const float* x     = (const float*)d_in[0];
  const float* w_enc = (const float*)d_in[1];
  const float* w_dec = (const float*)d_in[2];
  const float* b_enc = (const float*)d_in[3];
  const float* b_pre = (const float*)d_in[4];
  const int*   sln   = (const int*)d_in[5];

  float* out0 = (float*)d_out;                          // recons [4096][1024]
  float* out1 = out0 + (size_t)BATCH * IN_DIM;          // aux_recons
  float* out2 = out0 + 2 * (size_t)BATCH * IN_DIM;      // num_dead (as f32)

  char* ws = (char*)d_ws;
  size_t off = 0;
  auto take = [&](size_t bytes) { char* p = ws + off; off += (bytes + 255) & ~(size_t)255; return p; };

  // pre (half-batch f32, 128 MB) aliases A2 (full-batch bf16, 128 MB)
  float*  pre      = (float*)take((size_t)HALF_B * HID * 4);
  ushort* A2       = (ushort*)pre;
  ushort* wencT    = (ushort*)take((size_t)HID * IN_DIM * 2);
  ushort* wdecT    = (ushort*)take((size_t)HID * IN_DIM * 2);
  ushort* xh       = (ushort*)take((size_t)BATCH * IN_DIM * 2);
  ushort* part     = (ushort*)take((size_t)KSPLIT * BATCH * IN_DIM * 2);
  float*  mu       = (float*)take(BATCH * 4);
  float*  stdv     = (float*)take(BATCH * 4);
  int*    midx     = (int*)take((size_t)BATCH * KTOP * 4);
  float*  mval     = (float*)take((size_t)BATCH * KTOP * 4);
  int*    aidx     = (int*)take((size_t)BATCH * KAUX * 4);
  ushort* aval     = (ushort*)take((size_t)BATCH * KAUX * 2);
  int*    fired    = (int*)take(HID * 4);

  if (ws_size < off) {  // diagnostic: report actual ws_size through num_dead slot
    diag_kernel<<<1, 1, 0, stream>>>(out2, (float)ws_size);
    return;
  }

  ln_kernel<<<BATCH, 256, 0, stream>>>(x, b_pre, xh, mu, stdv);
  transpose_k<<<dim3(HID / 32, IN_DIM / 32), 256, 0, stream>>>(w_enc, wencT, IN_DIM, HID);
  transpose_k<<<dim3(IN_DIM / 32, HID / 32), 256, 0, stream>>>(w_dec, wdecT, HID, IN_DIM);
  hipMemsetAsync(fired, 0, HID * sizeof(int), stream);

  for (int half = 0; half < 2; ++half) {
    const ushort* Ah = xh + (size_t)half * HALF_B * IN_DIM;
    gemm256<0><<<dim3(HID / 256, HALF_B / 256, 1), 512, 0, stream>>>(
        Ah, wencT, pre, nullptr, b_enc, HALF_B, HID, IN_DIM, IN_DIM);
    topk2_kernel<<<HALF_B, 256, 0, stream>>>(pre, half * HALF_B, midx, mval, aidx, aval, fired);
  }
  stats_kernel<<<1, 256, 0, stream>>>(fired, sln, out2);

  hipMemsetAsync(A2, 0, (size_t)BATCH * HID * 2, stream);   // pre dead now
  scatter_aux<<<(BATCH * KAUX) / 256, 256, 0, stream>>>(aidx, aval, A2);

  gemm256<1><<<dim3(IN_DIM / 256, BATCH / 256, KSPLIT), 512, 0, stream>>>(
      A2, wdecT, nullptr, part, nullptr, BATCH, IN_DIM, HID, HID / KSPLIT);
  reduce_dec<<<(BATCH * IN_DIM) / 1024, 256, 0, stream>>>(part, b_pre, stdv, mu, out1);

  decode_main<<<BATCH, 256, 0, stream>>>(midx, mval, w_dec, b_pre, stdv, mu, out0);
}

// Round 7
// 702.227 us; speedup vs baseline: 3.0055x; 1.0502x over previous
//
#include <hip/hip_runtime.h>

#define BATCH 4096
#define HALF_B 2048
#define IN_DIM 1024
#define HID 16384
#define KTOP 64
#define KAUX 512
#define KSPLIT 4
#define LN_EPS 1e-5f
#define TIE_CAP 768
#define NBIN 2048

typedef short s16x8 __attribute__((ext_vector_type(8)));
typedef float f32x4 __attribute__((ext_vector_type(4)));

__device__ __forceinline__ ushort f2bf(float f) {
  unsigned u = __float_as_uint(f);
  u += 0x7FFFu + ((u >> 16) & 1u);   // RNE
  return (ushort)(u >> 16);
}
__device__ __forceinline__ float bf2f(ushort h) {
  return __uint_as_float(((unsigned)h) << 16);
}

__device__ __forceinline__ void gl_lds16(const void* g, void* l) {
  __builtin_amdgcn_global_load_lds(
      (const __attribute__((address_space(1))) unsigned*)g,
      (__attribute__((address_space(3))) unsigned*)l, 16, 0, 0);
}

#define BARRIER() do { __builtin_amdgcn_s_barrier(); asm volatile("" ::: "memory"); } while (0)

__device__ __forceinline__ float block_sum_f(float v) {
  __shared__ float redf[4];
  for (int o = 32; o > 0; o >>= 1) v += __shfl_down(v, o, 64);
  int lane = threadIdx.x & 63, w = threadIdx.x >> 6;
  if (lane == 0) redf[w] = v;
  __syncthreads();
  float t = (redf[0] + redf[1]) + (redf[2] + redf[3]);
  __syncthreads();
  return t;
}

__device__ __forceinline__ int block_sum_i(int v) {
  __shared__ int redi[4];
  for (int o = 32; o > 0; o >>= 1) v += __shfl_down(v, o, 64);
  int lane = threadIdx.x & 63, w = threadIdx.x >> 6;
  if (lane == 0) redi[w] = v;
  __syncthreads();
  int t = (redi[0] + redi[1]) + (redi[2] + redi[3]);
  __syncthreads();
  return t;
}

// ---------------- LayerNorm -> x_norm bf16, mu, std ----------------
__global__ __launch_bounds__(256) void ln_kernel(
    const float* __restrict__ x, const float* __restrict__ b_pre,
    ushort* __restrict__ xh, float* __restrict__ mu, float* __restrict__ stdv)
{
  int r = blockIdx.x, t = threadIdx.x;
  float4 v = ((const float4*)(x + (size_t)r * IN_DIM))[t];
  float s = (v.x + v.y) + (v.z + v.w);
  float mean = block_sum_f(s) * (1.0f / IN_DIM);
  float dx = v.x - mean, dy = v.y - mean, dz = v.z - mean, dw = v.w - mean;
  float ss = (dx*dx + dy*dy) + (dz*dz + dw*dw);
  float var = block_sum_f(ss) * (1.0f / (IN_DIM - 1));   // ddof = 1
  float sd = sqrtf(var);
  float inv = 1.0f / (sd + LN_EPS);
  float4 bp = ((const float4*)b_pre)[t];
  ushort h0 = f2bf(dx*inv - bp.x), h1 = f2bf(dy*inv - bp.y);
  ushort h2 = f2bf(dz*inv - bp.z), h3 = f2bf(dw*inv - bp.w);
  *(ushort4*)(xh + (size_t)r * IN_DIM + t * 4) = make_ushort4(h0, h1, h2, h3);
  if (t == 0) { mu[r] = mean; stdv[r] = sd; }
}

// ---------------- transpose f32 [R][C] -> bf16 [C][R] ----------------
__global__ __launch_bounds__(256) void transpose_k(
    const float* __restrict__ in, ushort* __restrict__ oh, int R, int C)
{
  __shared__ float tile[32][33];
  int c0 = blockIdx.x * 32, r0 = blockIdx.y * 32;
  int t = threadIdx.x;
  int col = t & 31, rbase = t >> 5;
  #pragma unroll
  for (int rep = 0; rep < 4; ++rep) {
    int rr = rbase + rep * 8;
    tile[rr][col] = in[(size_t)(r0 + rr) * C + c0 + col];
  }
  __syncthreads();
  int j = t & 31, ibase = t >> 5;
  #pragma unroll
  for (int rep = 0; rep < 4; ++rep) {
    int i = ibase + rep * 8;
    oh[(size_t)(c0 + i) * R + r0 + j] = f2bf(tile[j][i]);
  }
}

// ---- frag-read / MFMA helpers (compile-time indices only — rule #20) ----
#define RD_A4(DST, PA, MI0)                                                     \
  _Pragma("unroll")                                                             \
  for (int ks = 0; ks < 2; ++ks)                                                \
    _Pragma("unroll")                                                           \
    for (int i = 0; i < 4; ++i)                                                 \
      DST[ks][i] = *(const s16x8*)&PA[(wm * 128 + ((MI0) + i) * 16 + fr) * 64 + \
                                      (((ks * 4 + fq) ^ axr) * 8)];

#define RD_B2(DST, PB, NI0)                                                     \
  _Pragma("unroll")                                                             \
  for (int ks = 0; ks < 2; ++ks)                                                \
    _Pragma("unroll")                                                           \
    for (int n = 0; n < 2; ++n)                                                 \
      DST[ks][n] = *(const s16x8*)&PB[(wn * 64 + ((NI0) + n) * 16 + fr) * 64 +  \
                                      (((ks * 4 + fq) ^ axr) * 8)];

#define MFMA16(AF, BF, MI0, NI0)                                                \
  __builtin_amdgcn_s_setprio(1);                                                \
  _Pragma("unroll")                                                             \
  for (int ks = 0; ks < 2; ++ks)                                                \
    _Pragma("unroll")                                                           \
    for (int i = 0; i < 4; ++i)                                                 \
      _Pragma("unroll")                                                         \
      for (int n = 0; n < 2; ++n)                                               \
        acc[(MI0) + i][(NI0) + n] = __builtin_amdgcn_mfma_f32_16x16x32_bf16(    \
            AF[ks][i], BF[ks][n], acc[(MI0) + i][(NI0) + n], 0, 0, 0);          \
  __builtin_amdgcn_s_setprio(0);

// ---------------- GEMM C = A @ B^T, 256x256, 8-phase windows + counted vmcnt ------
// LDS: 2 buf x (A 256x64 | B 256x64) bf16 = 128 KiB. T2 both-sides XOR swizzle.
// MODE 0: C f32 = acc + bias[n]                       (encoder)
// MODE 1: C bf16 partial (split-K via blockIdx.z)     (decoder)
template<int MODE>
__global__ __launch_bounds__(512, 2) void gemm256(
    const ushort* __restrict__ A, const ushort* __restrict__ B,
    float* __restrict__ Cf, ushort* __restrict__ Cb,
    const float* __restrict__ bias, int M, int N, int K, int kchunk)
{
  __shared__ ushort lds[2 * 2 * 256 * 64];

  const int tid = threadIdx.x;
  const int w = tid >> 6, lane = tid & 63;
  const int fr = lane & 15, fq = lane >> 4;
  const int wm = w >> 2, wn = w & 3;
  const int axr = fr & 7;

  // XCD-aware swizzle over the xy-plane (nwg % 8 == 0 in all launches here)
  const int gx = gridDim.x, nwg = gx * gridDim.y;
  const int flat = blockIdx.y * gx + blockIdx.x;
  const int cpx = nwg >> 3;
  const int sw = (flat & 7) * cpx + (flat >> 3);
  const int bn0 = (sw % gx) * 256, bm0 = (sw / gx) * 256;
  const int kbeg = blockIdx.z * kchunk;

  const int srow = tid >> 3, sslot = tid & 7;

  // stage half h of K-tile kt: h 0,1 = A rows [0,128)/[128,256); h 2,3 = B same.
  auto STAGE_HALF = [&](int kt, int h) {
    const int k0 = kbeg + (kt << 6);
    const int lb = (kt & 1) * 32768 + (h >> 1) * 16384;
    #pragma unroll
    for (int q = 0; q < 2; ++q) {
      int row = (h & 1) * 128 + q * 64 + srow;
      int gcol = (sslot ^ (row & 7)) * 8;
      const ushort* src = (h < 2) ? (A + (size_t)(bm0 + row) * K)
                                  : (B + (size_t)(bn0 + row) * K);
      gl_lds16(src + k0 + gcol, &lds[lb + row * 64 + sslot * 8]);
    }
  };

  f32x4 acc[8][4] = {};
  const int nt = kchunk >> 6;

  #pragma unroll
  for (int h = 0; h < 4; ++h) STAGE_HALF(0, h);

  s16x8 af03[2][4], af47[2][4], bf01[2][2], bf23[2][2];

  for (int t = 0; t < nt; ++t) {
    const ushort* Ab = &lds[(t & 1) * 32768];
    const ushort* Bb = Ab + 16384;
    const bool more = (t + 1 < nt);

    // ---- P0: stage h0(next) + counted vmcnt; after bar, issue Q1 reads ----
    if (more) {
      STAGE_HALF(t + 1, 0);
      asm volatile("s_waitcnt vmcnt(2)" ::: "memory");   // tile t resident
    } else {
      asm volatile("s_waitcnt vmcnt(0)" ::: "memory");
    }
    BARRIER();
    RD_A4(af03, Ab, 0);
    RD_B2(bf01, Bb, 0);
    if (more) STAGE_HALF(t + 1, 1);
    BARRIER();
    // ---- P1: read bf23 | MFMA Q1 ----
    RD_B2(bf23, Bb, 2);
    MFMA16(af03, bf01, 0, 0);
    if (more) STAGE_HALF(t + 1, 2);
    BARRIER();
    // ---- P2: read af47 | MFMA Q2 ----
    RD_A4(af47, Ab, 4);
    MFMA16(af03, bf23, 0, 2);
    if (more) STAGE_HALF(t + 1, 3);
    BARRIER();
    // ---- P3: drain LDS reads, pure MFMA Q3+Q4 ----
    asm volatile("s_waitcnt lgkmcnt(0)" ::: "memory");
    __builtin_amdgcn_sched_barrier(0);                   // rule #18
    MFMA16(af47, bf01, 4, 0);
    MFMA16(af47, bf23, 4, 2);
  }

  #pragma unroll
  for (int mi = 0; mi < 8; ++mi) {
    int grow_b = bm0 + wm * 128 + mi * 16 + fq * 4;
    #pragma unroll
    for (int ni = 0; ni < 4; ++ni) {
      int gcol = bn0 + wn * 64 + ni * 16 + fr;
      #pragma unroll
      for (int q = 0; q < 4; ++q) {
        int grow = grow_b + q;
        if constexpr (MODE == 0) {
          Cf[(size_t)grow * N + gcol] = acc[mi][ni][q] + bias[gcol];
        } else {
          Cb[((size_t)blockIdx.z * M + grow) * N + gcol] = f2bf(acc[mi][ni][q]);
        }
      }
    }
  }
}

// ---------------- reduce split-K partials + decoder epilogue ----------------
__global__ __launch_bounds__(256) void reduce_dec(
    const ushort* __restrict__ P, const float* __restrict__ b_pre,
    const float* __restrict__ stdv, const float* __restrict__ muv,
    float* __restrict__ out)
{
  int gid = blockIdx.x * 256 + threadIdx.x;
  size_t e0 = (size_t)gid * 4;
  int r = (int)(e0 >> 10), c = (int)(e0 & 1023);
  float sx = 0.f, sy = 0.f, sz = 0.f, sw = 0.f;
  #pragma unroll
  for (int ks = 0; ks < KSPLIT; ++ks) {
    ushort4 p = *(const ushort4*)&P[(size_t)ks * BATCH * IN_DIM + e0];
    sx += bf2f(p.x); sy += bf2f(p.y); sz += bf2f(p.z); sw += bf2f(p.w);
  }
  float4 bp = *(const float4*)&b_pre[c];
  float s = stdv[r], m = muv[r];
  float4 o;
  o.x = (sx + bp.x) * s + m;
  o.y = (sy + bp.y) * s + m;
  o.z = (sz + bp.z) * s + m;
  o.w = (sw + bp.w) * s + m;
  *(float4*)&out[e0] = o;
}

// ---------------- top-k v2: register keys + two-level histogram select ------------
__device__ __forceinline__ unsigned key_of(float f) {
  unsigned u = __float_as_uint(f);
  return (u & 0x80000000u) ? ~u : (u | 0x80000000u);
}
__device__ __forceinline__ float val_of(unsigned k) {
  unsigned u = (k & 0x80000000u) ? (k & 0x7FFFFFFFu) : ~k;
  return __uint_as_float(u);
}

__device__ __forceinline__ void scan_find(int* hist, int t, int K1, int K2,
                                          int* res, int* wsum)
{
  int lane = t & 63, w = t >> 6;
  int h[8];
  #pragma unroll
  for (int j = 0; j < 8; ++j) h[j] = hist[t * 8 + j];
  int p = 0;
  #pragma unroll
  for (int j = 0; j < 8; ++j) p += h[j];
  int v = p;
  #pragma unroll
  for (int off = 1; off < 64; off <<= 1) {
    int o = __shfl_down(v, off, 64);
    if (lane + off < 64) v += o;
  }
  if (lane == 0) wsum[w] = v;
  __syncthreads();
  int above_w = 0;
  for (int ww = w + 1; ww < 4; ++ww) above_w += wsum[ww];
  int incl = v + above_w;
  int E = incl - p;                // suffix strictly above this thread's bins
  int S[9];
  S[8] = E;
  #pragma unroll
  for (int j = 7; j >= 0; --j) S[j] = h[j] + S[j + 1];
  #pragma unroll
  for (int j = 0; j < 8; ++j) hist[t * 8 + j] = S[j];
  #pragma unroll
  for (int j = 0; j < 8; ++j) {
    if (S[j] >= K1 && S[j + 1] < K1) { res[0] = t * 8 + j; res[1] = S[j + 1]; }
    if (S[j] >= K2 && S[j + 1] < K2) { res[2] = t * 8 + j; res[3] = S[j + 1]; }
  }
  __syncthreads();
}

__global__ __launch_bounds__(256) void topk2_kernel(
    const float* __restrict__ pre, int r0,
    int* __restrict__ midx, float* __restrict__ mval,
    int* __restrict__ aidx, ushort* __restrict__ aval,
    int* __restrict__ fired)
{
  const int rl = blockIdx.x, t = threadIdx.x;
  const int r = r0 + rl;
  __shared__ int histA[NBIN];
  __shared__ int histB[NBIN];
  __shared__ int wsum[4];
  __shared__ int res[12];
  __shared__ int tkey64[TIE_CAP], tidx64[TIE_CAP];
  __shared__ int tkey512[TIE_CAP], tidx512[TIE_CAP];
  __shared__ int cm, ca, c64, c512;

  unsigned key[64];
  const float4* src = (const float4*)(pre + (size_t)rl * HID);
  #pragma unroll
  for (int c = 0; c < 16; ++c) {
    float4 v = src[c * 256 + t];
    key[c * 4 + 0] = key_of(v.x); key[c * 4 + 1] = key_of(v.y);
    key[c * 4 + 2] = key_of(v.z); key[c * 4 + 3] = key_of(v.w);
  }
  #pragma unroll
  for (int j = 0; j < 8; ++j) histA[t * 8 + j] = 0;
  if (t == 0) { cm = 0; ca = 0; c64 = 0; c512 = 0; }
  __syncthreads();

  #pragma unroll
  for (int q = 0; q < 64; ++q) atomicAdd(&histA[key[q] >> 21], 1);
  __syncthreads();
  scan_find(histA, t, KTOP, KAUX, res, wsum);
  const int B64 = res[0], above64 = res[1], B512 = res[2], above512 = res[3];

  #pragma unroll
  for (int j = 0; j < 8; ++j) { histA[t * 8 + j] = 0; histB[t * 8 + j] = 0; }
  __syncthreads();
  #pragma unroll
  for (int q = 0; q < 64; ++q) {
    unsigned b = key[q] >> 21, sub = (key[q] >> 10) & 2047u;
    if (b == (unsigned)B64)  atomicAdd(&histA[sub], 1);
    if (b == (unsigned)B512) atomicAdd(&histB[sub], 1);
  }
  __syncthreads();
  scan_find(histA, t, KTOP - above64,  KTOP - above64,  res + 4, wsum);
  scan_find(histB, t, KAUX - above512, KAUX - above512, res + 8, wsum);

  const unsigned T64  = ((unsigned)B64  << 21) | ((unsigned)res[4] << 10);
  const unsigned T512 = ((unsigned)B512 << 21) | ((unsigned)res[8] << 10);
  const unsigned H64 = T64 + 1024u, H512 = T512 + 1024u;

  #pragma unroll
  for (int c = 0; c < 16; ++c) {
    #pragma unroll
    for (int j = 0; j < 4; ++j) {
      unsigned k = key[c * 4 + j];
      int i = c * 1024 + t * 4 + j;
      if (k >= H512) {
        int p = atomicAdd(&ca, 1);
        float v = val_of(k);
        aidx[(size_t)r * KAUX + p] = i;
        aval[(size_t)r * KAUX + p] = f2bf(v > 0.f ? v : 0.f);
      } else if (k >= T512) {
        int p = atomicAdd(&c512, 1);
        if (p < TIE_CAP) { tkey512[p] = (int)k; tidx512[p] = i; }
      }
      if (k >= H64) {
        int p = atomicAdd(&cm, 1);
        float v = val_of(k);
        midx[(size_t)r * KTOP + p] = i;
        mval[(size_t)r * KTOP + p] = v > 0.f ? v : 0.f;
        if (v > 0.f) fired[i] = 1;
      } else if (k >= T64) {
        int p = atomicAdd(&c64, 1);
        if (p < TIE_CAP) { tkey64[p] = (int)k; tidx64[p] = i; }
      }
    }
  }
  __syncthreads();

  if (t == 0) {
    int have = cm, nt = c64 < TIE_CAP ? c64 : TIE_CAP, need = KTOP - have;
    for (int q = 0; q < need; ++q) {
      int best = 0x7FFFFFFF, bi = -1;
      for (int u = 0; u < nt; ++u) if (tidx64[u] < best) { best = tidx64[u]; bi = u; }
      if (bi < 0) break;
      float v = val_of((unsigned)tkey64[bi]);
      tidx64[bi] = 0x7FFFFFFF;
      midx[(size_t)r * KTOP + have + q] = best;
      mval[(size_t)r * KTOP + have + q] = v > 0.f ? v : 0.f;
      if (v > 0.f) fired[best] = 1;
    }
  }
  if (t == 64) {
    int have = ca, nt = c512 < TIE_CAP ? c512 : TIE_CAP, need = KAUX - have;
    for (int q = 0; q < need; ++q) {
      int best = 0x7FFFFFFF, bi = -1;
      for (int u = 0; u < nt; ++u) if (tidx512[u] < best) { best = tidx512[u]; bi = u; }
      if (bi < 0) break;
      float v = val_of((unsigned)tkey512[bi]);
      tidx512[bi] = 0x7FFFFFFF;
      aidx[(size_t)r * KAUX + have + q] = best;
      aval[(size_t)r * KAUX + have + q] = f2bf(v > 0.f ? v : 0.f);
    }
  }
}

// ---------------- stats / num_dead ----------------
__global__ __launch_bounds__(256) void stats_kernel(
    const int* __restrict__ fired, const int* __restrict__ sln, float* __restrict__ nd_out)
{
  int t = threadIdx.x, c = 0;
  for (int j = t; j < HID; j += 256) {
    int dead = (fired[j] == 0) ? 1 : 0;
    int stats = sln[j] * dead + 1;
    if ((float)stats > (2000.0f / 4096.0f)) c++;
  }
  c = block_sum_i(c);
  if (t == 0) nd_out[0] = (float)c;
}

// ---------------- scatter aux latents into dense bf16 matrix ----------------
__global__ __launch_bounds__(256) void scatter_aux(
    const int* __restrict__ aidx, const ushort* __restrict__ aval, ushort* __restrict__ A2)
{
  int g = blockIdx.x * 256 + threadIdx.x;
  int r = g >> 9;
  int j = aidx[g];
  A2[(size_t)r * HID + j] = aval[g];
}

// ---------------- main decode: sparse gather, f32 exact ----------------
__global__ __launch_bounds__(256) void decode_main(
    const int* __restrict__ midx, const float* __restrict__ mval,
    const float* __restrict__ wdec, const float* __restrict__ b_pre,
    const float* __restrict__ stdv, const float* __restrict__ muv,
    float* __restrict__ out)
{
  int r = blockIdx.x, t = threadIdx.x;
  __shared__ int sj[KTOP];
  __shared__ float sv[KTOP];
  if (t < KTOP) { sj[t] = midx[(size_t)r * KTOP + t]; sv[t] = mval[(size_t)r * KTOP + t]; }
  __syncthreads();
  float ax = 0.f, ay = 0.f, az = 0.f, aw = 0.f;
  for (int i = 0; i < KTOP; ++i) {
    float v = sv[i];
    const float4* wrow = (const float4*)(wdec + (size_t)sj[i] * IN_DIM);
    float4 wv = wrow[t];
    ax += v * wv.x; ay += v * wv.y; az += v * wv.z; aw += v * wv.w;
  }
  float4 bp = ((const float4*)b_pre)[t];
  float s = stdv[r], m = muv[r];
  float4 o;
  o.x = (ax + bp.x) * s + m;
  o.y = (ay + bp.y) * s + m;
  o.z = (az + bp.z) * s + m;
  o.w = (aw + bp.w) * s + m;
  ((float4*)(out + (size_t)r * IN_DIM))[t] = o;
}

__global__ void diag_kernel(float* p, float v) { p[0] = v; }

// ---------------- launch ----------------
extern "C" void kernel_launch(void* const* d_in, const int* in_sizes, int n_in,
                              void* d_out, int out_size, void* d_ws, size_t ws_size,
                              hipStream_t stream)
{
  const float* x     = (const float*)d_in[0];
  const float* w_enc = (const float*)d_in[1];
  const float* w_dec = (const float*)d_in[2];
  const float* b_enc = (const float*)d_in[3];
  const float* b_pre = (const float*)d_in[4];
  const int*   sln   = (const int*)d_in[5];

  float* out0 = (float*)d_out;                          // recons [4096][1024]
  float* out1 = out0 + (size_t)BATCH * IN_DIM;          // aux_recons
  float* out2 = out0 + 2 * (size_t)BATCH * IN_DIM;      // num_dead (as f32)

  char* ws = (char*)d_ws;
  size_t off = 0;
  auto take = [&](size_t bytes) { char* p = ws + off; off += (bytes + 255) & ~(size_t)255; return p; };

  // pre (half-batch f32, 128 MB) aliases A2 (full-batch bf16, 128 MB)
  float*  pre      = (float*)take((size_t)HALF_B * HID * 4);
  ushort* A2       = (ushort*)pre;
  ushort* wencT    = (ushort*)take((size_t)HID * IN_DIM * 2);
  ushort* wdecT    = (ushort*)take((size_t)HID * IN_DIM * 2);
  ushort* xh       = (ushort*)take((size_t)BATCH * IN_DIM * 2);
  ushort* part     = (ushort*)take((size_t)KSPLIT * BATCH * IN_DIM * 2);
  float*  mu       = (float*)take(BATCH * 4);
  float*  stdv     = (float*)take(BATCH * 4);
  int*    midx     = (int*)take((size_t)BATCH * KTOP * 4);
  float*  mval     = (float*)take((size_t)BATCH * KTOP * 4);
  int*    aidx     = (int*)take((size_t)BATCH * KAUX * 4);
  ushort* aval     = (ushort*)take((size_t)BATCH * KAUX * 2);
  int*    fired    = (int*)take(HID * 4);

  if (ws_size < off) {  // diagnostic: report actual ws_size through num_dead slot
    diag_kernel<<<1, 1, 0, stream>>>(out2, (float)ws_size);
    return;
  }

  ln_kernel<<<BATCH, 256, 0, stream>>>(x, b_pre, xh, mu, stdv);
  transpose_k<<<dim3(HID / 32, IN_DIM / 32), 256, 0, stream>>>(w_enc, wencT, IN_DIM, HID);
  transpose_k<<<dim3(IN_DIM / 32, HID / 32), 256, 0, stream>>>(w_dec, wdecT, HID, IN_DIM);
  hipMemsetAsync(fired, 0, HID * sizeof(int), stream);

  for (int half = 0; half < 2; ++half) {
    const ushort* Ah = xh + (size_t)half * HALF_B * IN_DIM;
    gemm256<0><<<dim3(HID / 256, HALF_B / 256, 1), 512, 0, stream>>>(
        Ah, wencT, pre, nullptr, b_enc, HALF_B, HID, IN_DIM, IN_DIM);
    topk2_kernel<<<HALF_B, 256, 0, stream>>>(pre, half * HALF_B, midx, mval, aidx, aval, fired);
  }
  stats_kernel<<<1, 256, 0, stream>>>(fired, sln, out2);

  hipMemsetAsync(A2, 0, (size_t)BATCH * HID * 2, stream);   // pre dead now
  scatter_aux<<<(BATCH * KAUX) / 256, 256, 0, stream>>>(aidx, aval, A2);

  gemm256<1><<<dim3(IN_DIM / 256, BATCH / 256, KSPLIT), 512, 0, stream>>>(
      A2, wdecT, nullptr, part, nullptr, BATCH, IN_DIM, HID, HID / KSPLIT);
  reduce_dec<<<(BATCH * IN_DIM) / 1024, 256, 0, stream>>>(part, b_pre, stdv, mu, out1);

  decode_main<<<BATCH, 256, 0, stream>>>(midx, mval, w_dec, b_pre, stdv, mu, out0);
}

// Round 8
// 640.075 us; speedup vs baseline: 3.2973x; 1.0971x over previous
//
#include <hip/hip_runtime.h>

#define BATCH 4096
#define HALF_B 2048
#define IN_DIM 1024
#define HID 16384
#define KTOP 64
#define KAUX 512
#define KSPLIT 4
#define LN_EPS 1e-5f
#define TIE_CAP 768
#define NBIN 2048

typedef short s16x8 __attribute__((ext_vector_type(8)));
typedef float f32x4 __attribute__((ext_vector_type(4)));

__device__ __forceinline__ ushort f2bf(float f) {
  unsigned u = __float_as_uint(f);
  u += 0x7FFFu + ((u >> 16) & 1u);   // RNE
  return (ushort)(u >> 16);
}
__device__ __forceinline__ float bf2f(ushort h) {
  return __uint_as_float(((unsigned)h) << 16);
}

__device__ __forceinline__ void gl_lds16(const void* g, void* l) {
  __builtin_amdgcn_global_load_lds(
      (const __attribute__((address_space(1))) unsigned*)g,
      (__attribute__((address_space(3))) unsigned*)l, 16, 0, 0);
}

#define BARRIER() do { __builtin_amdgcn_s_barrier(); asm volatile("" ::: "memory"); } while (0)

__device__ __forceinline__ float block_sum_f(float v) {
  __shared__ float redf[4];
  for (int o = 32; o > 0; o >>= 1) v += __shfl_down(v, o, 64);
  int lane = threadIdx.x & 63, w = threadIdx.x >> 6;
  if (lane == 0) redf[w] = v;
  __syncthreads();
  float t = (redf[0] + redf[1]) + (redf[2] + redf[3]);
  __syncthreads();
  return t;
}

__device__ __forceinline__ int block_sum_i(int v) {
  __shared__ int redi[4];
  for (int o = 32; o > 0; o >>= 1) v += __shfl_down(v, o, 64);
  int lane = threadIdx.x & 63, w = threadIdx.x >> 6;
  if (lane == 0) redi[w] = v;
  __syncthreads();
  int t = (redi[0] + redi[1]) + (redi[2] + redi[3]);
  __syncthreads();
  return t;
}

// ---------------- LayerNorm -> x_norm bf16, mu, std ----------------
__global__ __launch_bounds__(256) void ln_kernel(
    const float* __restrict__ x, const float* __restrict__ b_pre,
    ushort* __restrict__ xh, float* __restrict__ mu, float* __restrict__ stdv)
{
  int r = blockIdx.x, t = threadIdx.x;
  float4 v = ((const float4*)(x + (size_t)r * IN_DIM))[t];
  float s = (v.x + v.y) + (v.z + v.w);
  float mean = block_sum_f(s) * (1.0f / IN_DIM);
  float dx = v.x - mean, dy = v.y - mean, dz = v.z - mean, dw = v.w - mean;
  float ss = (dx*dx + dy*dy) + (dz*dz + dw*dw);
  float var = block_sum_f(ss) * (1.0f / (IN_DIM - 1));   // ddof = 1
  float sd = sqrtf(var);
  float inv = 1.0f / (sd + LN_EPS);
  float4 bp = ((const float4*)b_pre)[t];
  ushort h0 = f2bf(dx*inv - bp.x), h1 = f2bf(dy*inv - bp.y);
  ushort h2 = f2bf(dz*inv - bp.z), h3 = f2bf(dw*inv - bp.w);
  *(ushort4*)(xh + (size_t)r * IN_DIM + t * 4) = make_ushort4(h0, h1, h2, h3);
  if (t == 0) { mu[r] = mean; stdv[r] = sd; }
}

// ---------------- transpose f32 [R][C] -> bf16 [C][R] (+optional row-major bf16) --
__global__ __launch_bounds__(256) void transpose_k(
    const float* __restrict__ in, ushort* __restrict__ oh,
    ushort* __restrict__ orow, int R, int C)
{
  __shared__ float tile[32][33];
  int c0 = blockIdx.x * 32, r0 = blockIdx.y * 32;
  int t = threadIdx.x;
  int col = t & 31, rbase = t >> 5;
  #pragma unroll
  for (int rep = 0; rep < 4; ++rep) {
    int rr = rbase + rep * 8;
    float v = in[(size_t)(r0 + rr) * C + c0 + col];
    tile[rr][col] = v;
    if (orow) orow[(size_t)(r0 + rr) * C + c0 + col] = f2bf(v);
  }
  __syncthreads();
  int j = t & 31, ibase = t >> 5;
  #pragma unroll
  for (int rep = 0; rep < 4; ++rep) {
    int i = ibase + rep * 8;
    oh[(size_t)(c0 + i) * R + r0 + j] = f2bf(tile[j][i]);
  }
}

// ---- frag-read / MFMA helpers (compile-time indices only — rule #20) ----
#define RD_A4(DST, PA, MI0)                                                     \
  _Pragma("unroll")                                                             \
  for (int ks = 0; ks < 2; ++ks)                                                \
    _Pragma("unroll")                                                           \
    for (int i = 0; i < 4; ++i)                                                 \
      DST[ks][i] = *(const s16x8*)&PA[(wm * 128 + ((MI0) + i) * 16 + fr) * 64 + \
                                      (((ks * 4 + fq) ^ axr) * 8)];

#define RD_B2(DST, PB, NI0)                                                     \
  _Pragma("unroll")                                                             \
  for (int ks = 0; ks < 2; ++ks)                                                \
    _Pragma("unroll")                                                           \
    for (int n = 0; n < 2; ++n)                                                 \
      DST[ks][n] = *(const s16x8*)&PB[(wn * 64 + ((NI0) + n) * 16 + fr) * 64 +  \
                                      (((ks * 4 + fq) ^ axr) * 8)];

#define MFMA16(AF, BF, MI0, NI0)                                                \
  __builtin_amdgcn_s_setprio(1);                                                \
  _Pragma("unroll")                                                             \
  for (int ks = 0; ks < 2; ++ks)                                                \
    _Pragma("unroll")                                                           \
    for (int i = 0; i < 4; ++i)                                                 \
      _Pragma("unroll")                                                         \
      for (int n = 0; n < 2; ++n)                                               \
        acc[(MI0) + i][(NI0) + n] = __builtin_amdgcn_mfma_f32_16x16x32_bf16(    \
            AF[ks][i], BF[ks][n], acc[(MI0) + i][(NI0) + n], 0, 0, 0);          \
  __builtin_amdgcn_s_setprio(0);

// ---------------- GEMM C = A @ B^T, 256x256, 8-phase windows + counted vmcnt ------
// LDS: 2 buf x (A 256x64 | B 256x64) bf16 = 128 KiB. T2 both-sides XOR swizzle.
// MODE 0: C f32 = acc + bias[n]                       (encoder)
// MODE 1: C bf16 partial (split-K via blockIdx.z)     (decoder)
template<int MODE>
__global__ __launch_bounds__(512, 2) void gemm256(
    const ushort* __restrict__ A, const ushort* __restrict__ B,
    float* __restrict__ Cf, ushort* __restrict__ Cb,
    const float* __restrict__ bias, int M, int N, int K, int kchunk)
{
  __shared__ ushort lds[2 * 2 * 256 * 64];

  const int tid = threadIdx.x;
  const int w = tid >> 6, lane = tid & 63;
  const int fr = lane & 15, fq = lane >> 4;
  const int wm = w >> 2, wn = w & 3;
  const int axr = fr & 7;

  // XCD-aware swizzle over the xy-plane (nwg % 8 == 0 in all launches here)
  const int gx = gridDim.x, nwg = gx * gridDim.y;
  const int flat = blockIdx.y * gx + blockIdx.x;
  const int cpx = nwg >> 3;
  const int sw = (flat & 7) * cpx + (flat >> 3);
  const int bn0 = (sw % gx) * 256, bm0 = (sw / gx) * 256;
  const int kbeg = blockIdx.z * kchunk;

  const int srow = tid >> 3, sslot = tid & 7;

  // stage half h of K-tile kt: h 0,1 = A rows [0,128)/[128,256); h 2,3 = B same.
  auto STAGE_HALF = [&](int kt, int h) {
    const int k0 = kbeg + (kt << 6);
    const int lb = (kt & 1) * 32768 + (h >> 1) * 16384;
    #pragma unroll
    for (int q = 0; q < 2; ++q) {
      int row = (h & 1) * 128 + q * 64 + srow;
      int gcol = (sslot ^ (row & 7)) * 8;
      const ushort* src = (h < 2) ? (A + (size_t)(bm0 + row) * K)
                                  : (B + (size_t)(bn0 + row) * K);
      gl_lds16(src + k0 + gcol, &lds[lb + row * 64 + sslot * 8]);
    }
  };

  f32x4 acc[8][4] = {};
  const int nt = kchunk >> 6;

  #pragma unroll
  for (int h = 0; h < 4; ++h) STAGE_HALF(0, h);

  s16x8 af03[2][4], af47[2][4], bf01[2][2], bf23[2][2];

  for (int t = 0; t < nt; ++t) {
    const ushort* Ab = &lds[(t & 1) * 32768];
    const ushort* Bb = Ab + 16384;
    const bool more = (t + 1 < nt);

    // ---- P0: stage h0(next) + counted vmcnt; after bar, issue Q1 reads ----
    if (more) {
      STAGE_HALF(t + 1, 0);
      asm volatile("s_waitcnt vmcnt(2)" ::: "memory");   // tile t resident
    } else {
      asm volatile("s_waitcnt vmcnt(0)" ::: "memory");
    }
    BARRIER();
    RD_A4(af03, Ab, 0);
    RD_B2(bf01, Bb, 0);
    if (more) STAGE_HALF(t + 1, 1);
    BARRIER();
    // ---- P1: read bf23 | MFMA Q1 ----
    RD_B2(bf23, Bb, 2);
    MFMA16(af03, bf01, 0, 0);
    if (more) STAGE_HALF(t + 1, 2);
    BARRIER();
    // ---- P2: read af47 | MFMA Q2 ----
    RD_A4(af47, Ab, 4);
    MFMA16(af03, bf23, 0, 2);
    if (more) STAGE_HALF(t + 1, 3);
    BARRIER();
    // ---- P3: drain LDS reads, pure MFMA Q3+Q4 ----
    asm volatile("s_waitcnt lgkmcnt(0)" ::: "memory");
    __builtin_amdgcn_sched_barrier(0);                   // rule #18
    MFMA16(af47, bf01, 4, 0);
    MFMA16(af47, bf23, 4, 2);
  }

  #pragma unroll
  for (int mi = 0; mi < 8; ++mi) {
    int grow_b = bm0 + wm * 128 + mi * 16 + fq * 4;
    #pragma unroll
    for (int ni = 0; ni < 4; ++ni) {
      int gcol = bn0 + wn * 64 + ni * 16 + fr;
      #pragma unroll
      for (int q = 0; q < 4; ++q) {
        int grow = grow_b + q;
        if constexpr (MODE == 0) {
          Cf[(size_t)grow * N + gcol] = acc[mi][ni][q] + bias[gcol];
        } else {
          Cb[((size_t)blockIdx.z * M + grow) * N + gcol] = f2bf(acc[mi][ni][q]);
        }
      }
    }
  }
}

// ---------------- reduce split-K partials + decoder epilogue ----------------
__global__ __launch_bounds__(256) void reduce_dec(
    const ushort* __restrict__ P, const float* __restrict__ b_pre,
    const float* __restrict__ stdv, const float* __restrict__ muv,
    float* __restrict__ out)
{
  int gid = blockIdx.x * 256 + threadIdx.x;
  size_t e0 = (size_t)gid * 4;
  int r = (int)(e0 >> 10), c = (int)(e0 & 1023);
  float sx = 0.f, sy = 0.f, sz = 0.f, sw = 0.f;
  #pragma unroll
  for (int ks = 0; ks < KSPLIT; ++ks) {
    ushort4 p = *(const ushort4*)&P[(size_t)ks * BATCH * IN_DIM + e0];
    sx += bf2f(p.x); sy += bf2f(p.y); sz += bf2f(p.z); sw += bf2f(p.w);
  }
  float4 bp = *(const float4*)&b_pre[c];
  float s = stdv[r], m = muv[r];
  float4 o;
  o.x = (sx + bp.x) * s + m;
  o.y = (sy + bp.y) * s + m;
  o.z = (sz + bp.z) * s + m;
  o.w = (sw + bp.w) * s + m;
  *(float4*)&out[e0] = o;
}

// ---------------- top-k v2: register keys + two-level histogram select ------------
__device__ __forceinline__ unsigned key_of(float f) {
  unsigned u = __float_as_uint(f);
  return (u & 0x80000000u) ? ~u : (u | 0x80000000u);
}
__device__ __forceinline__ float val_of(unsigned k) {
  unsigned u = (k & 0x80000000u) ? (k & 0x7FFFFFFFu) : ~k;
  return __uint_as_float(u);
}

__device__ __forceinline__ void scan_find(int* hist, int t, int K1, int K2,
                                          int* res, int* wsum)
{
  int lane = t & 63, w = t >> 6;
  int h[8];
  #pragma unroll
  for (int j = 0; j < 8; ++j) h[j] = hist[t * 8 + j];
  int p = 0;
  #pragma unroll
  for (int j = 0; j < 8; ++j) p += h[j];
  int v = p;
  #pragma unroll
  for (int off = 1; off < 64; off <<= 1) {
    int o = __shfl_down(v, off, 64);
    if (lane + off < 64) v += o;
  }
  if (lane == 0) wsum[w] = v;
  __syncthreads();
  int above_w = 0;
  for (int ww = w + 1; ww < 4; ++ww) above_w += wsum[ww];
  int incl = v + above_w;
  int E = incl - p;                // suffix strictly above this thread's bins
  int S[9];
  S[8] = E;
  #pragma unroll
  for (int j = 7; j >= 0; --j) S[j] = h[j] + S[j + 1];
  #pragma unroll
  for (int j = 0; j < 8; ++j) hist[t * 8 + j] = S[j];
  #pragma unroll
  for (int j = 0; j < 8; ++j) {
    if (S[j] >= K1 && S[j + 1] < K1) { res[0] = t * 8 + j; res[1] = S[j + 1]; }
    if (S[j] >= K2 && S[j + 1] < K2) { res[2] = t * 8 + j; res[3] = S[j + 1]; }
  }
  __syncthreads();
}

__global__ __launch_bounds__(256) void topk2_kernel(
    const float* __restrict__ pre, int r0,
    int* __restrict__ midx, float* __restrict__ mval,
    int* __restrict__ aidx, ushort* __restrict__ aval,
    int* __restrict__ fired)
{
  const int rl = blockIdx.x, t = threadIdx.x;
  const int r = r0 + rl;
  __shared__ int histA[NBIN];
  __shared__ int histB[NBIN];
  __shared__ int wsum[4];
  __shared__ int res[12];
  __shared__ int tkey64[TIE_CAP], tidx64[TIE_CAP];
  __shared__ int tkey512[TIE_CAP], tidx512[TIE_CAP];
  __shared__ int cm, ca, c64, c512;

  unsigned key[64];
  const float4* src = (const float4*)(pre + (size_t)rl * HID);
  #pragma unroll
  for (int c = 0; c < 16; ++c) {
    float4 v = src[c * 256 + t];
    key[c * 4 + 0] = key_of(v.x); key[c * 4 + 1] = key_of(v.y);
    key[c * 4 + 2] = key_of(v.z); key[c * 4 + 3] = key_of(v.w);
  }
  #pragma unroll
  for (int j = 0; j < 8; ++j) histA[t * 8 + j] = 0;
  if (t == 0) { cm = 0; ca = 0; c64 = 0; c512 = 0; }
  __syncthreads();

  #pragma unroll
  for (int q = 0; q < 64; ++q) atomicAdd(&histA[key[q] >> 21], 1);
  __syncthreads();
  scan_find(histA, t, KTOP, KAUX, res, wsum);
  const int B64 = res[0], above64 = res[1], B512 = res[2], above512 = res[3];

  #pragma unroll
  for (int j = 0; j < 8; ++j) { histA[t * 8 + j] = 0; histB[t * 8 + j] = 0; }
  __syncthreads();
  #pragma unroll
  for (int q = 0; q < 64; ++q) {
    unsigned b = key[q] >> 21, sub = (key[q] >> 10) & 2047u;
    if (b == (unsigned)B64)  atomicAdd(&histA[sub], 1);
    if (b == (unsigned)B512) atomicAdd(&histB[sub], 1);
  }
  __syncthreads();
  scan_find(histA, t, KTOP - above64,  KTOP - above64,  res + 4, wsum);
  scan_find(histB, t, KAUX - above512, KAUX - above512, res + 8, wsum);

  const unsigned T64  = ((unsigned)B64  << 21) | ((unsigned)res[4] << 10);
  const unsigned T512 = ((unsigned)B512 << 21) | ((unsigned)res[8] << 10);
  const unsigned H64 = T64 + 1024u, H512 = T512 + 1024u;

  #pragma unroll
  for (int c = 0; c < 16; ++c) {
    #pragma unroll
    for (int j = 0; j < 4; ++j) {
      unsigned k = key[c * 4 + j];
      int i = c * 1024 + t * 4 + j;
      if (k >= H512) {
        int p = atomicAdd(&ca, 1);
        float v = val_of(k);
        aidx[(size_t)r * KAUX + p] = i;
        aval[(size_t)r * KAUX + p] = f2bf(v > 0.f ? v : 0.f);
      } else if (k >= T512) {
        int p = atomicAdd(&c512, 1);
        if (p < TIE_CAP) { tkey512[p] = (int)k; tidx512[p] = i; }
      }
      if (k >= H64) {
        int p = atomicAdd(&cm, 1);
        float v = val_of(k);
        midx[(size_t)r * KTOP + p] = i;
        mval[(size_t)r * KTOP + p] = v > 0.f ? v : 0.f;
        if (v > 0.f) fired[i] = 1;
      } else if (k >= T64) {
        int p = atomicAdd(&c64, 1);
        if (p < TIE_CAP) { tkey64[p] = (int)k; tidx64[p] = i; }
      }
    }
  }
  __syncthreads();

  if (t == 0) {
    int have = cm, nt = c64 < TIE_CAP ? c64 : TIE_CAP, need = KTOP - have;
    for (int q = 0; q < need; ++q) {
      int best = 0x7FFFFFFF, bi = -1;
      for (int u = 0; u < nt; ++u) if (tidx64[u] < best) { best = tidx64[u]; bi = u; }
      if (bi < 0) break;
      float v = val_of((unsigned)tkey64[bi]);
      tidx64[bi] = 0x7FFFFFFF;
      midx[(size_t)r * KTOP + have + q] = best;
      mval[(size_t)r * KTOP + have + q] = v > 0.f ? v : 0.f;
      if (v > 0.f) fired[best] = 1;
    }
  }
  if (t == 64) {
    int have = ca, nt = c512 < TIE_CAP ? c512 : TIE_CAP, need = KAUX - have;
    for (int q = 0; q < need; ++q) {
      int best = 0x7FFFFFFF, bi = -1;
      for (int u = 0; u < nt; ++u) if (tidx512[u] < best) { best = tidx512[u]; bi = u; }
      if (bi < 0) break;
      float v = val_of((unsigned)tkey512[bi]);
      tidx512[bi] = 0x7FFFFFFF;
      aidx[(size_t)r * KAUX + have + q] = best;
      aval[(size_t)r * KAUX + have + q] = f2bf(v > 0.f ? v : 0.f);
    }
  }
}

// ---------------- stats / num_dead ----------------
__global__ __launch_bounds__(256) void stats_kernel(
    const int* __restrict__ fired, const int* __restrict__ sln, float* __restrict__ nd_out)
{
  int t = threadIdx.x, c = 0;
  for (int j = t; j < HID; j += 256) {
    int dead = (fired[j] == 0) ? 1 : 0;
    int stats = sln[j] * dead + 1;
    if ((float)stats > (2000.0f / 4096.0f)) c++;
  }
  c = block_sum_i(c);
  if (t == 0) nd_out[0] = (float)c;
}

// ---------------- scatter aux latents into dense bf16 matrix ----------------
__global__ __launch_bounds__(256) void scatter_aux(
    const int* __restrict__ aidx, const ushort* __restrict__ aval, ushort* __restrict__ A2)
{
  int g = blockIdx.x * 256 + threadIdx.x;
  int r = g >> 9;
  int j = aidx[g];
  A2[(size_t)r * HID + j] = aval[g];
}

// ---------------- main decode: sparse gather of bf16 w_dec, f32 accumulate --------
__global__ __launch_bounds__(256) void decode_main(
    const int* __restrict__ midx, const float* __restrict__ mval,
    const ushort* __restrict__ wdecB, const float* __restrict__ b_pre,
    const float* __restrict__ stdv, const float* __restrict__ muv,
    float* __restrict__ out)
{
  int r = blockIdx.x, t = threadIdx.x;
  __shared__ int sj[KTOP];
  __shared__ float sv[KTOP];
  if (t < KTOP) { sj[t] = midx[(size_t)r * KTOP + t]; sv[t] = mval[(size_t)r * KTOP + t]; }
  __syncthreads();
  float ax = 0.f, ay = 0.f, az = 0.f, aw = 0.f;
  #pragma unroll 4
  for (int i = 0; i < KTOP; ++i) {
    float v = sv[i];
    ushort4 wv = *(const ushort4*)(wdecB + (size_t)sj[i] * IN_DIM + t * 4);
    ax += v * bf2f(wv.x); ay += v * bf2f(wv.y);
    az += v * bf2f(wv.z); aw += v * bf2f(wv.w);
  }
  float4 bp = ((const float4*)b_pre)[t];
  float s = stdv[r], m = muv[r];
  float4 o;
  o.x = (ax + bp.x) * s + m;
  o.y = (ay + bp.y) * s + m;
  o.z = (az + bp.z) * s + m;
  o.w = (aw + bp.w) * s + m;
  ((float4*)(out + (size_t)r * IN_DIM))[t] = o;
}

__global__ void diag_kernel(float* p, float v) { p[0] = v; }

// ---------------- launch ----------------
extern "C" void kernel_launch(void* const* d_in, const int* in_sizes, int n_in,
                              void* d_out, int out_size, void* d_ws, size_t ws_size,
                              hipStream_t stream)
{
  const float* x     = (const float*)d_in[0];
  const float* w_enc = (const float*)d_in[1];
  const float* w_dec = (const float*)d_in[2];
  const float* b_enc = (const float*)d_in[3];
  const float* b_pre = (const float*)d_in[4];
  const int*   sln   = (const int*)d_in[5];

  float* out0 = (float*)d_out;                          // recons [4096][1024]
  float* out1 = out0 + (size_t)BATCH * IN_DIM;          // aux_recons
  float* out2 = out0 + 2 * (size_t)BATCH * IN_DIM;      // num_dead (as f32)

  char* ws = (char*)d_ws;
  size_t off = 0;
  auto take = [&](size_t bytes) { char* p = ws + off; off += (bytes + 255) & ~(size_t)255; return p; };

  // pre (half-batch f32, 128 MB) aliases A2 (full-batch bf16, 128 MB)
  float*  pre      = (float*)take((size_t)HALF_B * HID * 4);
  ushort* A2       = (ushort*)pre;
  ushort* wencT    = (ushort*)take((size_t)HID * IN_DIM * 2);
  ushort* wdecT    = (ushort*)take((size_t)HID * IN_DIM * 2);
  ushort* xh       = (ushort*)take((size_t)BATCH * IN_DIM * 2);
  // wdecB (row-major bf16 w_dec, 32 MB) aliases part (split-K partials, 32 MB):
  // wdecB is consumed by decode_main, which runs BEFORE gemm256<1> writes part.
  char*   u32      = take((size_t)KSPLIT * BATCH * IN_DIM * 2);
  ushort* part     = (ushort*)u32;
  ushort* wdecB    = (ushort*)u32;
  float*  mu       = (float*)take(BATCH * 4);
  float*  stdv     = (float*)take(BATCH * 4);
  int*    midx     = (int*)take((size_t)BATCH * KTOP * 4);
  float*  mval     = (float*)take((size_t)BATCH * KTOP * 4);
  int*    aidx     = (int*)take((size_t)BATCH * KAUX * 4);
  ushort* aval     = (ushort*)take((size_t)BATCH * KAUX * 2);
  int*    fired    = (int*)take(HID * 4);

  if (ws_size < off) {  // diagnostic: report actual ws_size through num_dead slot
    diag_kernel<<<1, 1, 0, stream>>>(out2, (float)ws_size);
    return;
  }

  ln_kernel<<<BATCH, 256, 0, stream>>>(x, b_pre, xh, mu, stdv);
  transpose_k<<<dim3(HID / 32, IN_DIM / 32), 256, 0, stream>>>(w_enc, wencT, nullptr, IN_DIM, HID);
  transpose_k<<<dim3(IN_DIM / 32, HID / 32), 256, 0, stream>>>(w_dec, wdecT, wdecB, HID, IN_DIM);
  hipMemsetAsync(fired, 0, HID * sizeof(int), stream);

  for (int half = 0; half < 2; ++half) {
    const ushort* Ah = xh + (size_t)half * HALF_B * IN_DIM;
    gemm256<0><<<dim3(HID / 256, HALF_B / 256, 1), 512, 0, stream>>>(
        Ah, wencT, pre, nullptr, b_enc, HALF_B, HID, IN_DIM, IN_DIM);
    topk2_kernel<<<HALF_B, 256, 0, stream>>>(pre, half * HALF_B, midx, mval, aidx, aval, fired);
  }
  stats_kernel<<<1, 256, 0, stream>>>(fired, sln, out2);

  // main decode first: consumes wdecB before gemm256<1> overwrites it with part
  decode_main<<<BATCH, 256, 0, stream>>>(midx, mval, wdecB, b_pre, stdv, mu, out0);

  hipMemsetAsync(A2, 0, (size_t)BATCH * HID * 2, stream);   // pre dead now
  scatter_aux<<<(BATCH * KAUX) / 256, 256, 0, stream>>>(aidx, aval, A2);

  gemm256<1><<<dim3(IN_DIM / 256, BATCH / 256, KSPLIT), 512, 0, stream>>>(
      A2, wdecT, nullptr, part, nullptr, BATCH, IN_DIM, HID, HID / KSPLIT);
  reduce_dec<<<(BATCH * IN_DIM) / 1024, 256, 0, stream>>>(part, b_pre, stdv, mu, out1);
}